// Round 1
// baseline (1144.184 us; speedup 1.0000x reference)
//
#include <hip/hip_runtime.h>
#include <math.h>

#define B_DIM 2
#define U_DIM 8
#define V_DIM 1024
#define C_DIM 256
#define H_DIM 4
#define KQ_DIM 64
#define CODE_DIM 192
#define EPS_A 1e-6f
#define GAIN_F 2.5f
#define ROWS 16
#define TSB 64

// ---------------- kernel 0: per-u modulation scales s[p][u][c] ----------
__global__ __launch_bounds__(256) void k_scales(
    const float* __restrict__ codes,
    const float* __restrict__ qWc, const float* __restrict__ kWc,
    const float* __restrict__ vWc, const float* __restrict__ m1Wc,
    const float* __restrict__ m2Wc, float* __restrict__ s_all) {
  int p = blockIdx.x / U_DIM;
  int u = blockIdx.x % U_DIM;
  const float* Wc = (p == 0) ? qWc : (p == 1) ? kWc : (p == 2) ? vWc
                    : (p == 3) ? m1Wc : m2Wc;
  __shared__ float cs[CODE_DIM];
  int t = threadIdx.x;
  if (t < CODE_DIM) cs[t] = codes[u * CODE_DIM + t];
  __syncthreads();
  float acc = 0.f;
  for (int j = 0; j < CODE_DIM; ++j) acc += cs[j] * Wc[j * C_DIM + t];
  s_all[(p * U_DIM + u) * C_DIM + t] = acc;
}

// ---------------- kernel A: LN1 + modulated QKV projections -------------
__global__ __launch_bounds__(256) void k_qkv(
    const float* __restrict__ vars,
    const float* __restrict__ ln1g, const float* __restrict__ ln1b,
    const float* __restrict__ qW, const float* __restrict__ kW,
    const float* __restrict__ vW, const float* __restrict__ vbias,
    const float* __restrict__ s_all,
    float* __restrict__ qo, float* __restrict__ ko, float* __restrict__ vo) {
  const int bid = blockIdx.x;
  const int row0 = bid * ROWS;          // global row in [B*U*V]
  const int bu = row0 / V_DIM;
  const int u = bu % U_DIM;
  const int t = threadIdx.x;

  __shared__ __align__(16) float xr[ROWS][C_DIM];
  __shared__ float xs2[ROWS][C_DIM];
  __shared__ float mean_s[ROWS], rstd_s[ROWS];

  const float4* src = (const float4*)(vars + (size_t)row0 * C_DIM);
  float4* xrf = (float4*)&xr[0][0];
#pragma unroll
  for (int i = 0; i < (ROWS * C_DIM) / 1024; ++i) xrf[i * 256 + t] = src[i * 256 + t];
  __syncthreads();

  const int wave = t >> 6, lane = t & 63;
#pragma unroll
  for (int rr = 0; rr < ROWS / 4; ++rr) {
    const int r = wave * (ROWS / 4) + rr;
    float s1 = 0.f, s2 = 0.f;
#pragma unroll
    for (int i = 0; i < C_DIM / 64; ++i) { float x = xr[r][lane + 64 * i]; s1 += x; s2 += x * x; }
#pragma unroll
    for (int off = 32; off; off >>= 1) { s1 += __shfl_xor(s1, off); s2 += __shfl_xor(s2, off); }
    if (lane == 0) {
      float mm = s1 * (1.f / C_DIM);
      float var = s2 * (1.f / C_DIM) - mm * mm;
      mean_s[r] = mm; rstd_s[r] = rsqrtf(var + 1e-5f);
    }
  }

  const float g = ln1g[t], bb = ln1b[t];
  const int h = t >> 6, ch = t & 63;

  for (int p = 0; p < 3; ++p) {
    __syncthreads();   // also covers mean_s/rstd_s for p==0
    const float sp = s_all[(p * U_DIM + u) * C_DIM + t];
#pragma unroll
    for (int i = 0; i < ROWS; ++i) {
      float val = (xr[i][t] - mean_s[i]) * rstd_s[i] * g + bb;
      xs2[i][t] = val * sp;
    }
    __syncthreads();
    const float* W = (p == 0) ? qW : (p == 1) ? kW : vW;
    float acc[ROWS];
#pragma unroll
    for (int i = 0; i < ROWS; ++i) acc[i] = 0.f;
#pragma unroll 4
    for (int c = 0; c < C_DIM; ++c) {
      const float w = W[c * C_DIM + t];
#pragma unroll
      for (int r = 0; r < ROWS; ++r) acc[r] += xs2[r][c] * w;  // xs2 read = LDS broadcast
    }
    float* dst = (p == 0) ? qo : (p == 1) ? ko : vo;
    const float badd = (p == 2) ? vbias[t] : 0.f;
    const size_t base = (((size_t)bu * H_DIM + h) * V_DIM + (row0 % V_DIM)) * KQ_DIM + ch;
#pragma unroll
    for (int r = 0; r < ROWS; ++r) dst[base + (size_t)r * KQ_DIM] = acc[r] + badd;
  }
}

// ---------------- kernel B: flash attention + affinity renorm + gate ----
__global__ __launch_bounds__(256) void k_attn(
    const float* __restrict__ q, const float* __restrict__ k,
    const float* __restrict__ v, const float* __restrict__ aff,
    const float* __restrict__ vars, float* __restrict__ out) {
  const int nrt = V_DIM / 256;
  const int bid = blockIdx.x;
  const int rt = bid % nrt;
  const int buh = bid / nrt;
  const int bu = buh / H_DIM;
  const int h = buh % H_DIM;
  const int t = threadIdx.x;
  const int r = rt * 256 + t;

  const float* qb = q + (size_t)buh * V_DIM * KQ_DIM;
  const float* kb = k + (size_t)buh * V_DIM * KQ_DIM;
  const float* vb = v + (size_t)buh * V_DIM * KQ_DIM;
  const float* ab = aff + (size_t)bu * V_DIM;

  float4 qr[16];
  const float4* qsrc = (const float4*)(qb + (size_t)r * KQ_DIM);
#pragma unroll
  for (int i = 0; i < 16; ++i) qr[i] = qsrc[i];
  const float a_r = ab[r];

  __shared__ __align__(16) float kl[TSB][KQ_DIM];
  __shared__ __align__(16) float vl[TSB][KQ_DIM];

  float m = -INFINITY, Z = 0.f, Y = 0.f;
  float4 acc[16];
#pragma unroll
  for (int i = 0; i < 16; ++i) acc[i] = make_float4(0.f, 0.f, 0.f, 0.f);

  for (int st = 0; st < V_DIM / TSB; ++st) {
    __syncthreads();
    const float4* ks = (const float4*)(kb + (size_t)st * TSB * KQ_DIM);
    const float4* vs = (const float4*)(vb + (size_t)st * TSB * KQ_DIM);
    float4* kld = (float4*)&kl[0][0];
    float4* vld = (float4*)&vl[0][0];
#pragma unroll
    for (int i = 0; i < (TSB * KQ_DIM) / 1024; ++i) {
      kld[i * 256 + t] = ks[i * 256 + t];
      vld[i * 256 + t] = vs[i * 256 + t];
    }
    __syncthreads();
    const int s0 = st * TSB;
    for (int s = 0; s < TSB; ++s) {
      const float4* kr = (const float4*)&kl[s][0];
      float sc = 0.f;
#pragma unroll
      for (int i = 0; i < 16; ++i) {
        float4 kk = kr[i];
        sc += qr[i].x * kk.x + qr[i].y * kk.y + qr[i].z * kk.z + qr[i].w * kk.w;
      }
      const float a_s = ab[s0 + s];
      if (sc > m) {
        const float scale = __expf(m - sc);
        m = sc; Z *= scale; Y *= scale;
#pragma unroll
        for (int i = 0; i < 16; ++i) {
          acc[i].x *= scale; acc[i].y *= scale; acc[i].z *= scale; acc[i].w *= scale;
        }
      }
      const float e = __expf(sc - m);
      Z += e;
      const float w = a_s * e;
      Y += w;
      const float4* vr = (const float4*)&vl[s][0];
#pragma unroll
      for (int i = 0; i < 16; ++i) {
        float4 vv = vr[i];
        acc[i].x += w * vv.x; acc[i].y += w * vv.y;
        acc[i].z += w * vv.z; acc[i].w += w * vv.w;
      }
    }
  }

  // kmw_norm = a_s e_s * t/(t*Y+EPS), t = a_r/Z  (Z >= 1 always)
  const float tt = a_r / Z;
  const float den = tt * Y + EPS_A;
  const float f = tt / den;
  const float g1 = 1.f - a_r;
  const float g2 = a_r * GAIN_F * f;
  const float* vrow = vars + ((size_t)bu * V_DIM + r) * C_DIM + h * KQ_DIM;
  float* orow = out + ((size_t)bu * V_DIM + r) * C_DIM + h * KQ_DIM;
#pragma unroll
  for (int i = 0; i < 16; ++i) {
    float4 x = ((const float4*)vrow)[i];
    float4 o;
    o.x = g1 * x.x + g2 * acc[i].x;
    o.y = g1 * x.y + g2 * acc[i].y;
    o.z = g1 * x.z + g2 * acc[i].z;
    o.w = g1 * x.w + g2 * acc[i].w;
    ((float4*)orow)[i] = o;
  }
}

// ---------------- kernel C: LN2 + modulated MLP + gating (in-place) -----
__global__ __launch_bounds__(256) void k_mlp(
    const float* __restrict__ aff,
    const float* __restrict__ ln2g, const float* __restrict__ ln2b,
    const float* __restrict__ m1W, const float* __restrict__ m1b,
    const float* __restrict__ m2W, const float* __restrict__ m2b,
    const float* __restrict__ s_all, float* __restrict__ io) {
  const int bid = blockIdx.x;
  const int row0 = bid * ROWS;
  const int bu = row0 / V_DIM;
  const int u = bu % U_DIM;
  const int t = threadIdx.x;

  __shared__ __align__(16) float xr[ROWS][C_DIM];
  __shared__ float xs2[ROWS][C_DIM];
  __shared__ float mean_s[ROWS], rstd_s[ROWS], a_row[ROWS];

  const float4* src = (const float4*)(io + (size_t)row0 * C_DIM);
  float4* xrf = (float4*)&xr[0][0];
#pragma unroll
  for (int i = 0; i < (ROWS * C_DIM) / 1024; ++i) xrf[i * 256 + t] = src[i * 256 + t];
  if (t < ROWS) a_row[t] = aff[row0 + t];
  __syncthreads();

  const int wave = t >> 6, lane = t & 63;
#pragma unroll
  for (int rr = 0; rr < ROWS / 4; ++rr) {
    const int r = wave * (ROWS / 4) + rr;
    float s1 = 0.f, s2 = 0.f;
#pragma unroll
    for (int i = 0; i < C_DIM / 64; ++i) { float x = xr[r][lane + 64 * i]; s1 += x; s2 += x * x; }
#pragma unroll
    for (int off = 32; off; off >>= 1) { s1 += __shfl_xor(s1, off); s2 += __shfl_xor(s2, off); }
    if (lane == 0) {
      float mm = s1 * (1.f / C_DIM);
      float var = s2 * (1.f / C_DIM) - mm * mm;
      mean_s[r] = mm; rstd_s[r] = rsqrtf(var + 1e-5f);
    }
  }
  __syncthreads();

  const float g = ln2g[t], bb = ln2b[t];
  const float sm1 = s_all[(3 * U_DIM + u) * C_DIM + t];
  const float sm2 = s_all[(4 * U_DIM + u) * C_DIM + t];
#pragma unroll
  for (int i = 0; i < ROWS; ++i) {
    float val = (xr[i][t] - mean_s[i]) * rstd_s[i] * g + bb;
    xs2[i][t] = val * sm1;
  }
  __syncthreads();

  float acc[ROWS];
#pragma unroll
  for (int i = 0; i < ROWS; ++i) acc[i] = 0.f;
  const float b1 = m1b[t];
#pragma unroll 4
  for (int c = 0; c < C_DIM; ++c) {
    const float w = m1W[c * C_DIM + t];
#pragma unroll
    for (int r = 0; r < ROWS; ++r) acc[r] += xs2[r][c] * w;
  }
  __syncthreads();
#pragma unroll
  for (int r = 0; r < ROWS; ++r) {
    float x = acc[r] + b1;
    float ge = 0.5f * x * (1.f + erff(x * 0.70710678118f));
    xs2[r][t] = ge * sm2;
  }
  __syncthreads();

#pragma unroll
  for (int i = 0; i < ROWS; ++i) acc[i] = 0.f;
  const float b2 = m2b[t];
#pragma unroll 4
  for (int c = 0; c < C_DIM; ++c) {
    const float w = m2W[c * C_DIM + t];
#pragma unroll
    for (int r = 0; r < ROWS; ++r) acc[r] += xs2[r][c] * w;
  }

  float* drow = io + (size_t)row0 * C_DIM;
#pragma unroll
  for (int r = 0; r < ROWS; ++r) {
    float x = acc[r] + b2;
    float ge = 0.5f * x * (1.f + erff(x * 0.70710678118f));
    const float a = a_row[r];
    drow[(size_t)r * C_DIM + t] = (1.f - a) * xr[r][t] + a * a * GAIN_F * ge;
  }
}

extern "C" void kernel_launch(void* const* d_in, const int* in_sizes, int n_in,
                              void* d_out, int out_size, void* d_ws, size_t ws_size,
                              hipStream_t stream) {
  const float* vars  = (const float*)d_in[0];
  const float* codes = (const float*)d_in[1];
  const float* aff   = (const float*)d_in[2];
  const float* ln1g  = (const float*)d_in[3];
  const float* ln1b  = (const float*)d_in[4];
  const float* ln2g  = (const float*)d_in[5];
  const float* ln2b  = (const float*)d_in[6];
  const float* qWc   = (const float*)d_in[7];
  const float* qW    = (const float*)d_in[8];
  const float* kWc   = (const float*)d_in[9];
  const float* kW    = (const float*)d_in[10];
  const float* vWc   = (const float*)d_in[11];
  const float* vW    = (const float*)d_in[12];
  const float* vb    = (const float*)d_in[13];
  const float* m1Wc  = (const float*)d_in[14];
  const float* m1W   = (const float*)d_in[15];
  const float* m1b   = (const float*)d_in[16];
  const float* m2Wc  = (const float*)d_in[17];
  const float* m2W   = (const float*)d_in[18];
  const float* m2b   = (const float*)d_in[19];
  float* out = (float*)d_out;

  float* s_all = (float*)d_ws;                       // 5*8*256 floats
  const size_t headsz = (size_t)B_DIM * U_DIM * H_DIM * V_DIM * KQ_DIM;
  float* qo = s_all + 5 * U_DIM * C_DIM;
  float* ko = qo + headsz;
  float* vo = ko + headsz;

  k_scales<<<5 * U_DIM, 256, 0, stream>>>(codes, qWc, kWc, vWc, m1Wc, m2Wc, s_all);
  k_qkv<<<(B_DIM * U_DIM * V_DIM) / ROWS, 256, 0, stream>>>(
      vars, ln1g, ln1b, qW, kW, vW, vb, s_all, qo, ko, vo);
  k_attn<<<B_DIM * U_DIM * H_DIM * (V_DIM / 256), 256, 0, stream>>>(
      qo, ko, vo, aff, vars, out);
  k_mlp<<<(B_DIM * U_DIM * V_DIM) / ROWS, 256, 0, stream>>>(
      aff, ln2g, ln2b, m1W, m1b, m2W, m2b, s_all, out);
}

// Round 5
// 786.228 us; speedup vs baseline: 1.4553x; 1.4553x over previous
//
#include <hip/hip_runtime.h>
#include <math.h>

#define B_DIM 2
#define U_DIM 8
#define V_DIM 1024
#define C_DIM 256
#define H_DIM 4
#define KQ_DIM 64
#define CODE_DIM 192
#define EPS_A 1e-6f
#define GAIN_F 2.5f
#define ROWS 16
#define TSB 64
#define BUH (B_DIM * U_DIM * H_DIM)   // 64
#define NRT (V_DIM / 256)             // 4 row-tiles per buh

// ---------------- kernel 0: per-u modulation scales s[p][u][c] ----------
__global__ __launch_bounds__(256) void k_scales(
    const float* __restrict__ codes,
    const float* __restrict__ qWc, const float* __restrict__ kWc,
    const float* __restrict__ vWc, const float* __restrict__ m1Wc,
    const float* __restrict__ m2Wc, float* __restrict__ s_all) {
  int p = blockIdx.x / U_DIM;
  int u = blockIdx.x % U_DIM;
  const float* Wc = (p == 0) ? qWc : (p == 1) ? kWc : (p == 2) ? vWc
                    : (p == 3) ? m1Wc : m2Wc;
  __shared__ float cs[CODE_DIM];
  int t = threadIdx.x;
  if (t < CODE_DIM) cs[t] = codes[u * CODE_DIM + t];
  __syncthreads();
  float acc = 0.f;
  for (int j = 0; j < CODE_DIM; ++j) acc += cs[j] * Wc[j * C_DIM + t];
  s_all[(p * U_DIM + u) * C_DIM + t] = acc;
}

// ---------------- kernel A: LN1 + modulated QKV projections -------------
__global__ __launch_bounds__(256) void k_qkv(
    const float* __restrict__ vars,
    const float* __restrict__ ln1g, const float* __restrict__ ln1b,
    const float* __restrict__ qW, const float* __restrict__ kW,
    const float* __restrict__ vW, const float* __restrict__ vbias,
    const float* __restrict__ s_all,
    float* __restrict__ qo, float* __restrict__ ko, float* __restrict__ vo) {
  const int bid = blockIdx.x;
  const int row0 = bid * ROWS;          // global row in [B*U*V]
  const int bu = row0 / V_DIM;
  const int u = bu % U_DIM;
  const int t = threadIdx.x;

  __shared__ __align__(16) float xr[ROWS][C_DIM];
  __shared__ __align__(16) float xs2[ROWS][C_DIM];
  __shared__ float mean_s[ROWS], rstd_s[ROWS];

  const float4* src = (const float4*)(vars + (size_t)row0 * C_DIM);
  float4* xrf = (float4*)&xr[0][0];
#pragma unroll
  for (int i = 0; i < (ROWS * C_DIM) / 1024; ++i) xrf[i * 256 + t] = src[i * 256 + t];
  __syncthreads();

  const int wave = t >> 6, lane = t & 63;
#pragma unroll
  for (int rr = 0; rr < ROWS / 4; ++rr) {
    const int r = wave * (ROWS / 4) + rr;
    float s1 = 0.f, s2 = 0.f;
#pragma unroll
    for (int i = 0; i < C_DIM / 64; ++i) { float x = xr[r][lane + 64 * i]; s1 += x; s2 += x * x; }
#pragma unroll
    for (int off = 32; off; off >>= 1) { s1 += __shfl_xor(s1, off); s2 += __shfl_xor(s2, off); }
    if (lane == 0) {
      float mm = s1 * (1.f / C_DIM);
      float var = s2 * (1.f / C_DIM) - mm * mm;
      mean_s[r] = mm; rstd_s[r] = rsqrtf(var + 1e-5f);
    }
  }

  const float g = ln1g[t], bb = ln1b[t];
  const int h = t >> 6, ch = t & 63;

  for (int p = 0; p < 3; ++p) {
    __syncthreads();   // also covers mean_s/rstd_s for p==0
    const float sp = s_all[(p * U_DIM + u) * C_DIM + t];
#pragma unroll
    for (int i = 0; i < ROWS; ++i) {
      float val = (xr[i][t] - mean_s[i]) * rstd_s[i] * g + bb;
      xs2[i][t] = val * sp;
    }
    __syncthreads();
    const float* W = (p == 0) ? qW : (p == 1) ? kW : vW;
    float acc[ROWS];
#pragma unroll
    for (int i = 0; i < ROWS; ++i) acc[i] = 0.f;
#pragma unroll 2
    for (int c = 0; c < C_DIM; c += 4) {
      const float w0 = W[(c + 0) * C_DIM + t];
      const float w1 = W[(c + 1) * C_DIM + t];
      const float w2 = W[(c + 2) * C_DIM + t];
      const float w3 = W[(c + 3) * C_DIM + t];
#pragma unroll
      for (int r = 0; r < ROWS; ++r) {
        const float4 x4 = *(const float4*)&xs2[r][c];   // LDS broadcast b128
        acc[r] = fmaf(x4.x, w0, fmaf(x4.y, w1, fmaf(x4.z, w2, fmaf(x4.w, w3, acc[r]))));
      }
    }
    float* dst = (p == 0) ? qo : (p == 1) ? ko : vo;
    const float badd = (p == 2) ? vbias[t] : 0.f;
    const size_t base = (((size_t)bu * H_DIM + h) * V_DIM + (row0 % V_DIM)) * KQ_DIM + ch;
#pragma unroll
    for (int r = 0; r < ROWS; ++r) dst[base + (size_t)r * KQ_DIM] = acc[r] + badd;
  }
}

// ------- kernel B1: split-K flash attention partials (+ epilogue if split==1)
__global__ __launch_bounds__(256) void k_attn_part(
    const float* __restrict__ q, const float* __restrict__ k,
    const float* __restrict__ v, const float* __restrict__ aff,
    const float* __restrict__ vars, float* __restrict__ out,
    float* __restrict__ part, float4* __restrict__ stats, int split) {
  const int bid = blockIdx.x;
  const int ck = bid % split;
  const int rt = (bid / split) % NRT;
  const int buh = bid / (split * NRT);
  const int bu = buh / H_DIM;
  const int h = buh % H_DIM;
  const int t = threadIdx.x;
  const int r = rt * 256 + t;

  const float* qb = q + (size_t)buh * V_DIM * KQ_DIM;
  const float* kb = k + (size_t)buh * V_DIM * KQ_DIM;
  const float* vb = v + (size_t)buh * V_DIM * KQ_DIM;
  const float* ab = aff + (size_t)bu * V_DIM;

  float4 qr[16];
  const float4* qsrc = (const float4*)(qb + (size_t)r * KQ_DIM);
#pragma unroll
  for (int i = 0; i < 16; ++i) qr[i] = qsrc[i];
  const float a_r = ab[r];

  __shared__ __align__(16) float kl[TSB][KQ_DIM];
  __shared__ __align__(16) float vl[TSB][KQ_DIM];
  __shared__ __align__(16) float al[TSB];

  float m = -INFINITY, Z = 0.f, Y = 0.f;
  float4 acc[16];
#pragma unroll
  for (int i = 0; i < 16; ++i) acc[i] = make_float4(0.f, 0.f, 0.f, 0.f);

  const int chunk = V_DIM / split;
  const int s_begin = ck * chunk;
  const int ntiles = chunk / TSB;

  for (int st = 0; st < ntiles; ++st) {
    const int s0 = s_begin + st * TSB;
    __syncthreads();
    const float4* ks = (const float4*)(kb + (size_t)s0 * KQ_DIM);
    const float4* vs = (const float4*)(vb + (size_t)s0 * KQ_DIM);
    float4* kld = (float4*)&kl[0][0];
    float4* vld = (float4*)&vl[0][0];
#pragma unroll
    for (int i = 0; i < (TSB * KQ_DIM) / 1024; ++i) {
      kld[i * 256 + t] = ks[i * 256 + t];
      vld[i * 256 + t] = vs[i * 256 + t];
    }
    if (t < TSB / 4) ((float4*)al)[t] = ((const float4*)(ab + s0))[t];
    __syncthreads();
    for (int s = 0; s < TSB; ++s) {
      const float4* kr = (const float4*)&kl[s][0];
      float sx = 0.f, sy = 0.f, sz = 0.f, sw = 0.f;   // 4 chains for ILP
#pragma unroll
      for (int i = 0; i < 16; ++i) {
        const float4 kk = kr[i];
        sx = fmaf(qr[i].x, kk.x, sx);
        sy = fmaf(qr[i].y, kk.y, sy);
        sz = fmaf(qr[i].z, kk.z, sz);
        sw = fmaf(qr[i].w, kk.w, sw);
      }
      const float sc = (sx + sy) + (sz + sw);
      if (sc > m) {
        const float scale = __expf(m - sc);
        m = sc; Z *= scale; Y *= scale;
#pragma unroll
        for (int i = 0; i < 16; ++i) {
          acc[i].x *= scale; acc[i].y *= scale; acc[i].z *= scale; acc[i].w *= scale;
        }
      }
      const float e = __expf(sc - m);
      Z += e;
      const float w = al[s] * e;
      Y += w;
      const float4* vr = (const float4*)&vl[s][0];
#pragma unroll
      for (int i = 0; i < 16; ++i) {
        const float4 vv = vr[i];
        acc[i].x = fmaf(w, vv.x, acc[i].x);
        acc[i].y = fmaf(w, vv.y, acc[i].y);
        acc[i].z = fmaf(w, vv.z, acc[i].z);
        acc[i].w = fmaf(w, vv.w, acc[i].w);
      }
    }
  }

  if (split == 1) {
    const float tt = a_r / Z;
    const float den = tt * Y + EPS_A;
    const float f = tt / den;
    const float g1 = 1.f - a_r;
    const float g2 = a_r * GAIN_F * f;
    const float* vrow = vars + ((size_t)bu * V_DIM + r) * C_DIM + h * KQ_DIM;
    float* orow = out + ((size_t)bu * V_DIM + r) * C_DIM + h * KQ_DIM;
#pragma unroll
    for (int i = 0; i < 16; ++i) {
      float4 x = ((const float4*)vrow)[i];
      float4 o;
      o.x = g1 * x.x + g2 * acc[i].x;
      o.y = g1 * x.y + g2 * acc[i].y;
      o.z = g1 * x.z + g2 * acc[i].z;
      o.w = g1 * x.w + g2 * acc[i].w;
      ((float4*)orow)[i] = o;
    }
  } else {
    float4* prow = (float4*)(part + (((size_t)buh * split + ck) * V_DIM + r) * KQ_DIM);
#pragma unroll
    for (int i = 0; i < 16; ++i) prow[i] = acc[i];
    stats[((size_t)buh * split + ck) * V_DIM + r] = make_float4(m, Z, Y, 0.f);
  }
}

// ------- kernel B2: merge split-K partials + affinity renorm + gate -----
__global__ __launch_bounds__(256) void k_attn_merge(
    const float* __restrict__ part, const float4* __restrict__ stats,
    const float* __restrict__ aff, const float* __restrict__ vars,
    float* __restrict__ out, int split) {
  const int nrb = V_DIM / 32;            // 32 rows per block
  const int buh = blockIdx.x / nrb;
  const int r0 = (blockIdx.x % nrb) * 32;
  const int bu = buh / H_DIM;
  const int h = buh % H_DIM;
  const int t = threadIdx.x;
  const int rl = t >> 3;                 // 32 rows
  const int d0 = (t & 7) * 8;            // 8 dims per thread
  const int r = r0 + rl;

  float M = -INFINITY;
  float4 st[8];
  for (int c = 0; c < split; ++c) {
    st[c] = stats[((size_t)buh * split + c) * V_DIM + r];
    M = fmaxf(M, st[c].x);
  }
  float Z = 0.f, Y = 0.f;
  float acc[8];
#pragma unroll
  for (int i = 0; i < 8; ++i) acc[i] = 0.f;
  for (int c = 0; c < split; ++c) {
    const float w = __expf(st[c].x - M);
    Z = fmaf(w, st[c].y, Z);
    Y = fmaf(w, st[c].z, Y);
    const float4* p = (const float4*)(part +
        (((size_t)buh * split + c) * V_DIM + r) * KQ_DIM + d0);
    const float4 p0 = p[0], p1 = p[1];
    acc[0] = fmaf(w, p0.x, acc[0]); acc[1] = fmaf(w, p0.y, acc[1]);
    acc[2] = fmaf(w, p0.z, acc[2]); acc[3] = fmaf(w, p0.w, acc[3]);
    acc[4] = fmaf(w, p1.x, acc[4]); acc[5] = fmaf(w, p1.y, acc[5]);
    acc[6] = fmaf(w, p1.z, acc[6]); acc[7] = fmaf(w, p1.w, acc[7]);
  }
  const float a_r = aff[(size_t)bu * V_DIM + r];
  const float tt = a_r / Z;
  const float den = tt * Y + EPS_A;
  const float f = tt / den;
  const float g1 = 1.f - a_r;
  const float g2 = a_r * GAIN_F * f;
  const float* vrow = vars + ((size_t)bu * V_DIM + r) * C_DIM + h * KQ_DIM + d0;
  float* orow = out + ((size_t)bu * V_DIM + r) * C_DIM + h * KQ_DIM + d0;
  const float4 x0 = ((const float4*)vrow)[0];
  const float4 x1 = ((const float4*)vrow)[1];
  float4 o0, o1;
  o0.x = g1 * x0.x + g2 * acc[0]; o0.y = g1 * x0.y + g2 * acc[1];
  o0.z = g1 * x0.z + g2 * acc[2]; o0.w = g1 * x0.w + g2 * acc[3];
  o1.x = g1 * x1.x + g2 * acc[4]; o1.y = g1 * x1.y + g2 * acc[5];
  o1.z = g1 * x1.z + g2 * acc[6]; o1.w = g1 * x1.w + g2 * acc[7];
  ((float4*)orow)[0] = o0;
  ((float4*)orow)[1] = o1;
}

// ---------------- kernel C: LN2 + modulated MLP + gating (in-place) -----
__global__ __launch_bounds__(256) void k_mlp(
    const float* __restrict__ aff,
    const float* __restrict__ ln2g, const float* __restrict__ ln2b,
    const float* __restrict__ m1W, const float* __restrict__ m1b,
    const float* __restrict__ m2W, const float* __restrict__ m2b,
    const float* __restrict__ s_all, float* __restrict__ io) {
  const int bid = blockIdx.x;
  const int row0 = bid * ROWS;
  const int bu = row0 / V_DIM;
  const int u = bu % U_DIM;
  const int t = threadIdx.x;

  __shared__ __align__(16) float xr[ROWS][C_DIM];
  __shared__ __align__(16) float xs2[ROWS][C_DIM];
  __shared__ float mean_s[ROWS], rstd_s[ROWS], a_row[ROWS];

  const float4* src = (const float4*)(io + (size_t)row0 * C_DIM);
  float4* xrf = (float4*)&xr[0][0];
#pragma unroll
  for (int i = 0; i < (ROWS * C_DIM) / 1024; ++i) xrf[i * 256 + t] = src[i * 256 + t];
  if (t < ROWS) a_row[t] = aff[row0 + t];
  __syncthreads();

  const int wave = t >> 6, lane = t & 63;
#pragma unroll
  for (int rr = 0; rr < ROWS / 4; ++rr) {
    const int r = wave * (ROWS / 4) + rr;
    float s1 = 0.f, s2 = 0.f;
#pragma unroll
    for (int i = 0; i < C_DIM / 64; ++i) { float x = xr[r][lane + 64 * i]; s1 += x; s2 += x * x; }
#pragma unroll
    for (int off = 32; off; off >>= 1) { s1 += __shfl_xor(s1, off); s2 += __shfl_xor(s2, off); }
    if (lane == 0) {
      float mm = s1 * (1.f / C_DIM);
      float var = s2 * (1.f / C_DIM) - mm * mm;
      mean_s[r] = mm; rstd_s[r] = rsqrtf(var + 1e-5f);
    }
  }
  __syncthreads();

  const float g = ln2g[t], bb = ln2b[t];
  const float sm1 = s_all[(3 * U_DIM + u) * C_DIM + t];
  const float sm2 = s_all[(4 * U_DIM + u) * C_DIM + t];
#pragma unroll
  for (int i = 0; i < ROWS; ++i) {
    float val = (xr[i][t] - mean_s[i]) * rstd_s[i] * g + bb;
    xs2[i][t] = val * sm1;
  }
  __syncthreads();

  float acc[ROWS];
#pragma unroll
  for (int i = 0; i < ROWS; ++i) acc[i] = 0.f;
  const float b1 = m1b[t];
#pragma unroll 2
  for (int c = 0; c < C_DIM; c += 4) {
    const float w0 = m1W[(c + 0) * C_DIM + t];
    const float w1 = m1W[(c + 1) * C_DIM + t];
    const float w2 = m1W[(c + 2) * C_DIM + t];
    const float w3 = m1W[(c + 3) * C_DIM + t];
#pragma unroll
    for (int r = 0; r < ROWS; ++r) {
      const float4 x4 = *(const float4*)&xs2[r][c];
      acc[r] = fmaf(x4.x, w0, fmaf(x4.y, w1, fmaf(x4.z, w2, fmaf(x4.w, w3, acc[r]))));
    }
  }
  __syncthreads();
#pragma unroll
  for (int r = 0; r < ROWS; ++r) {
    float x = acc[r] + b1;
    float ge = 0.5f * x * (1.f + erff(x * 0.70710678118f));
    xs2[r][t] = ge * sm2;
  }
  __syncthreads();

#pragma unroll
  for (int i = 0; i < ROWS; ++i) acc[i] = 0.f;
  const float b2 = m2b[t];
#pragma unroll 2
  for (int c = 0; c < C_DIM; c += 4) {
    const float w0 = m2W[(c + 0) * C_DIM + t];
    const float w1 = m2W[(c + 1) * C_DIM + t];
    const float w2 = m2W[(c + 2) * C_DIM + t];
    const float w3 = m2W[(c + 3) * C_DIM + t];
#pragma unroll
    for (int r = 0; r < ROWS; ++r) {
      const float4 x4 = *(const float4*)&xs2[r][c];
      acc[r] = fmaf(x4.x, w0, fmaf(x4.y, w1, fmaf(x4.z, w2, fmaf(x4.w, w3, acc[r]))));
    }
  }

  float* drow = io + (size_t)row0 * C_DIM;
#pragma unroll
  for (int r = 0; r < ROWS; ++r) {
    float x = acc[r] + b2;
    float ge = 0.5f * x * (1.f + erff(x * 0.70710678118f));
    const float a = a_row[r];
    drow[(size_t)r * C_DIM + t] = (1.f - a) * xr[r][t] + a * a * GAIN_F * ge;
  }
}

extern "C" void kernel_launch(void* const* d_in, const int* in_sizes, int n_in,
                              void* d_out, int out_size, void* d_ws, size_t ws_size,
                              hipStream_t stream) {
  const float* vars  = (const float*)d_in[0];
  const float* codes = (const float*)d_in[1];
  const float* aff   = (const float*)d_in[2];
  const float* ln1g  = (const float*)d_in[3];
  const float* ln1b  = (const float*)d_in[4];
  const float* ln2g  = (const float*)d_in[5];
  const float* ln2b  = (const float*)d_in[6];
  const float* qWc   = (const float*)d_in[7];
  const float* qW    = (const float*)d_in[8];
  const float* kWc   = (const float*)d_in[9];
  const float* kW    = (const float*)d_in[10];
  const float* vWc   = (const float*)d_in[11];
  const float* vW    = (const float*)d_in[12];
  const float* vb    = (const float*)d_in[13];
  const float* m1Wc  = (const float*)d_in[14];
  const float* m1W   = (const float*)d_in[15];
  const float* m1b   = (const float*)d_in[16];
  const float* m2Wc  = (const float*)d_in[17];
  const float* m2W   = (const float*)d_in[18];
  const float* m2b   = (const float*)d_in[19];
  float* out = (float*)d_out;

  const size_t headsz = (size_t)B_DIM * U_DIM * H_DIM * V_DIM * KQ_DIM;  // 4.19M
  const size_t s_all_sz = 5 * U_DIM * C_DIM;

  // choose split by workspace capacity
  int split = 4;
  {
    auto need = [&](int s) -> size_t {
      size_t fl = s_all_sz + 3 * headsz;
      if (s > 1) fl += (size_t)BUH * s * V_DIM * KQ_DIM      // part
                     + (size_t)BUH * s * V_DIM * 4;          // stats (float4)
      return fl * 4;
    };
    if (ws_size < need(4)) split = (ws_size >= need(2)) ? 2 : 1;
  }

  float* s_all = (float*)d_ws;
  float* qo = s_all + s_all_sz;
  float* ko = qo + headsz;
  float* vo = ko + headsz;
  float* part = vo + headsz;
  float4* stats = (float4*)(part + (size_t)BUH * split * V_DIM * KQ_DIM);

  k_scales<<<5 * U_DIM, 256, 0, stream>>>(codes, qWc, kWc, vWc, m1Wc, m2Wc, s_all);
  k_qkv<<<(B_DIM * U_DIM * V_DIM) / ROWS, 256, 0, stream>>>(
      vars, ln1g, ln1b, qW, kW, vW, vb, s_all, qo, ko, vo);
  k_attn_part<<<BUH * NRT * split, 256, 0, stream>>>(
      qo, ko, vo, aff, vars, out, part, stats, split);
  if (split > 1) {
    k_attn_merge<<<BUH * (V_DIM / 32), 256, 0, stream>>>(
        part, stats, aff, vars, out, split);
  }
  k_mlp<<<(B_DIM * U_DIM * V_DIM) / ROWS, 256, 0, stream>>>(
      aff, ln2g, ln2b, m1W, m1b, m2W, m2b, s_all, out);
}

// Round 8
// 425.152 us; speedup vs baseline: 2.6912x; 1.8493x over previous
//
#include <hip/hip_runtime.h>
#include <math.h>

#define B_DIM 2
#define U_DIM 8
#define V_DIM 1024
#define C_DIM 256
#define H_DIM 4
#define KQ_DIM 64
#define CODE_DIM 192
#define EPS_A 1e-6f
#define GAIN_F 2.5f
#define ROWS 16
#define BUH (B_DIM * U_DIM * H_DIM)   // 64

typedef __attribute__((ext_vector_type(8))) short short8;
typedef __attribute__((ext_vector_type(4))) float f32x4;
typedef unsigned short ushort_t;
typedef unsigned int uint_t;

__device__ __forceinline__ ushort_t f2bf(float x) {
  union { float f; uint_t u; } v; v.f = x;
  uint_t r = v.u + 0x7FFFu + ((v.u >> 16) & 1u);   // round-nearest-even
  return (ushort_t)(r >> 16);
}
__device__ __forceinline__ float bf2f(ushort_t u) {
  union { uint_t u; float f; } v; v.u = ((uint_t)u) << 16; return v.f;
}
__device__ __forceinline__ uint_t pack2bf(float a, float b) {
  return (uint_t)f2bf(a) | ((uint_t)f2bf(b) << 16);
}

// ---------------- kernel 0: per-u modulation scales s[p][u][c] ----------
__global__ __launch_bounds__(256) void k_scales(
    const float* __restrict__ codes,
    const float* __restrict__ qWc, const float* __restrict__ kWc,
    const float* __restrict__ vWc, const float* __restrict__ m1Wc,
    const float* __restrict__ m2Wc, float* __restrict__ s_all) {
  int p = blockIdx.x / U_DIM;
  int u = blockIdx.x % U_DIM;
  const float* Wc = (p == 0) ? qWc : (p == 1) ? kWc : (p == 2) ? vWc
                    : (p == 3) ? m1Wc : m2Wc;
  __shared__ float cs[CODE_DIM];
  int t = threadIdx.x;
  if (t < CODE_DIM) cs[t] = codes[u * CODE_DIM + t];
  __syncthreads();
  float acc = 0.f;
  for (int j = 0; j < CODE_DIM; ++j) acc += cs[j] * Wc[j * C_DIM + t];
  s_all[(p * U_DIM + u) * C_DIM + t] = acc;
}

// -- kernel A: LN1 + modulated QKV projections (Q/K hi+lo bf16, V bf16) --
__global__ __launch_bounds__(256) void k_qkv(
    const float* __restrict__ vars,
    const float* __restrict__ ln1g, const float* __restrict__ ln1b,
    const float* __restrict__ qW, const float* __restrict__ kW,
    const float* __restrict__ vW, const float* __restrict__ vbias,
    const float* __restrict__ s_all,
    ushort_t* __restrict__ qh_g, ushort_t* __restrict__ ql_g,
    ushort_t* __restrict__ kh_g, ushort_t* __restrict__ kl_g,
    ushort_t* __restrict__ vo_g) {
  const int bid = blockIdx.x;
  const int row0 = bid * ROWS;          // global row in [B*U*V]
  const int bu = row0 / V_DIM;
  const int u = bu % U_DIM;
  const int t = threadIdx.x;

  __shared__ __align__(16) float xr[ROWS][C_DIM];
  __shared__ __align__(16) float xs2[ROWS][C_DIM];
  __shared__ float mean_s[ROWS], rstd_s[ROWS];

  const float4* src = (const float4*)(vars + (size_t)row0 * C_DIM);
  float4* xrf = (float4*)&xr[0][0];
#pragma unroll
  for (int i = 0; i < (ROWS * C_DIM) / 1024; ++i) xrf[i * 256 + t] = src[i * 256 + t];
  __syncthreads();

  const int wave = t >> 6, lane = t & 63;
#pragma unroll
  for (int rr = 0; rr < ROWS / 4; ++rr) {
    const int r = wave * (ROWS / 4) + rr;
    float s1 = 0.f, s2 = 0.f;
#pragma unroll
    for (int i = 0; i < C_DIM / 64; ++i) { float x = xr[r][lane + 64 * i]; s1 += x; s2 += x * x; }
#pragma unroll
    for (int off = 32; off; off >>= 1) { s1 += __shfl_xor(s1, off); s2 += __shfl_xor(s2, off); }
    if (lane == 0) {
      float mm = s1 * (1.f / C_DIM);
      float var = s2 * (1.f / C_DIM) - mm * mm;
      mean_s[r] = mm; rstd_s[r] = rsqrtf(var + 1e-5f);
    }
  }

  const float g = ln1g[t], bb = ln1b[t];
  const int h = t >> 6, ch = t & 63;

  for (int p = 0; p < 3; ++p) {
    __syncthreads();
    const float sp = s_all[(p * U_DIM + u) * C_DIM + t];
#pragma unroll
    for (int i = 0; i < ROWS; ++i) {
      float val = (xr[i][t] - mean_s[i]) * rstd_s[i] * g + bb;
      xs2[i][t] = val * sp;
    }
    __syncthreads();
    const float* W = (p == 0) ? qW : (p == 1) ? kW : vW;
    float acc[ROWS];
#pragma unroll
    for (int i = 0; i < ROWS; ++i) acc[i] = 0.f;
#pragma unroll 2
    for (int c = 0; c < C_DIM; c += 4) {
      const float w0 = W[(c + 0) * C_DIM + t];
      const float w1 = W[(c + 1) * C_DIM + t];
      const float w2 = W[(c + 2) * C_DIM + t];
      const float w3 = W[(c + 3) * C_DIM + t];
#pragma unroll
      for (int r = 0; r < ROWS; ++r) {
        const float4 x4 = *(const float4*)&xs2[r][c];
        acc[r] = fmaf(x4.x, w0, fmaf(x4.y, w1, fmaf(x4.z, w2, fmaf(x4.w, w3, acc[r]))));
      }
    }
    const size_t base = (((size_t)bu * H_DIM + h) * V_DIM + (row0 % V_DIM)) * KQ_DIM + ch;
    if (p < 2) {
      ushort_t* dh = (p == 0) ? qh_g : kh_g;
      ushort_t* dl = (p == 0) ? ql_g : kl_g;
#pragma unroll
      for (int r = 0; r < ROWS; ++r) {
        const float a = acc[r];
        const ushort_t hh = f2bf(a);
        dh[base + (size_t)r * KQ_DIM] = hh;
        dl[base + (size_t)r * KQ_DIM] = f2bf(a - bf2f(hh));
      }
    } else {
      const float badd = vbias[t];
#pragma unroll
      for (int r = 0; r < ROWS; ++r)
        vo_g[base + (size_t)r * KQ_DIM] = f2bf(acc[r] + badd);
    }
  }
}

// ------- kernel B: fused MFMA attention (hi/lo QK; folded a/Y/Z) --------
// grid: 512 = 64 buh * 8 row-blocks, bid = rb*64 + buh so all 8 row-blocks
// of one buh share an XCD (bid%8 == buh%8) for K/V L2 reuse.
__global__ __launch_bounds__(512) void k_attn_mfma(
    const ushort_t* __restrict__ qh, const ushort_t* __restrict__ ql,
    const ushort_t* __restrict__ kh, const ushort_t* __restrict__ kl,
    const ushort_t* __restrict__ v, const float* __restrict__ aff,
    const float* __restrict__ vars, float* __restrict__ out) {
  const int bid = blockIdx.x;
  const int buh = bid & 63;
  const int rb = bid >> 6;            // 0..7, 128 rows each
  const int bu = buh >> 2;
  const int head = buh & 3;
  const int t = threadIdx.x;
  const int w = t >> 6;               // wave 0..7
  const int lane = t & 63;
  const int g = lane >> 4;            // lane group 0..3
  const int i = lane & 15;

  const ushort_t* qhb = qh + (size_t)buh * V_DIM * KQ_DIM;
  const ushort_t* qlb = ql + (size_t)buh * V_DIM * KQ_DIM;
  const ushort_t* khb = kh + (size_t)buh * V_DIM * KQ_DIM;
  const ushort_t* klb = kl + (size_t)buh * V_DIM * KQ_DIM;
  const ushort_t* vb  = v  + (size_t)buh * V_DIM * KQ_DIM;
  const float* ab = aff + (size_t)bu * V_DIM;

  // K tiles [32 s][64 k] bf16, XOR-swizzled: elem = s*64 + (kk ^ ((s&7)<<3))
  __shared__ ushort_t klh[32 * 64];
  __shared__ ushort_t kll[32 * 64];
  // V'^T tile [80 d][32 s] bf16 (rows 0-63: a_s*V; 64: a_s; 65: 1)
  // swizzled: elem = d*32 + (s ^ (8*(d&3)))
  __shared__ ushort_t vt[80 * 32];

  const int R = rb * 128 + w * 16 + i;     // this lane's query row

  // Q B-fragments: slot j of half hh holds Q[R][hh*32 + 8g + j]
  union { uint4 u4; short8 s8; } qfh0, qfh1, qfl0, qfl1;
  qfh0.u4 = *(const uint4*)(qhb + (size_t)R * 64 + 0 * 32 + 8 * g);
  qfh1.u4 = *(const uint4*)(qhb + (size_t)R * 64 + 1 * 32 + 8 * g);
  qfl0.u4 = *(const uint4*)(qlb + (size_t)R * 64 + 0 * 32 + 8 * g);
  qfl1.u4 = *(const uint4*)(qlb + (size_t)R * 64 + 1 * 32 + 8 * g);

  f32x4 accO0 = {0.f,0.f,0.f,0.f}, accO1 = {0.f,0.f,0.f,0.f};
  f32x4 accO2 = {0.f,0.f,0.f,0.f}, accO3 = {0.f,0.f,0.f,0.f};
  f32x4 accYZ = {0.f,0.f,0.f,0.f};
  const f32x4 zf = {0.f,0.f,0.f,0.f};

  // staging indices
  const int ks_s = t >> 4;                  // 0..31
  const int ks_k = (t & 15) * 4;            // 0..60
  const int vs_s = t & 31;                  // 0..31
  const int vs_d0 = (t >> 5) * 4;           // 0..60

  for (int tile = 0; tile < V_DIM / 32; ++tile) {
    const int s0 = tile * 32;
    __syncthreads();   // previous tile's readers done
    // ---- stage K hi/lo tiles ----
    {
      const uint2 kvh = *(const uint2*)(khb + (size_t)(s0 + ks_s) * 64 + ks_k);
      const uint2 kvl = *(const uint2*)(klb + (size_t)(s0 + ks_s) * 64 + ks_k);
      const int dsti = ks_s * 64 + (ks_k ^ ((ks_s & 7) << 3));
      *(uint2*)&klh[dsti] = kvh;
      *(uint2*)&kll[dsti] = kvl;
    }
    // ---- stage V'^T tile (transpose + fold a_s; plus rows 64/65) ----
    {
      const float a_s = ab[s0 + vs_s];
      const uint2 vv = *(const uint2*)(vb + (size_t)(s0 + vs_s) * 64 + vs_d0);
      const ushort_t* ve = (const ushort_t*)&vv;
#pragma unroll
      for (int qq = 0; qq < 4; ++qq) {
        const int d = vs_d0 + qq;
        vt[d * 32 + (vs_s ^ (8 * (d & 3)))] = f2bf(a_s * bf2f(ve[qq]));
      }
      if (t < 32) {
        vt[64 * 32 + (vs_s ^ 0)] = f2bf(a_s);     // d=64: d&3=0
        vt[65 * 32 + (vs_s ^ 8)] = 0x3F80u;       // d=65: 1.0bf16, d&3=1
      }
    }
    __syncthreads();

    // ---- S^T = K x Q^T : 3-term hi/lo compensation, K-contraction 64 ----
    f32x4 Dst0 = zf, Dst1 = zf;
#pragma unroll
    for (int st = 0; st < 2; ++st) {
      const int srow = st * 16 + i;
      const int i0 = srow * 64 + ((0 * 32 + 8 * g) ^ ((srow & 7) << 3));
      const int i1 = srow * 64 + ((1 * 32 + 8 * g) ^ ((srow & 7) << 3));
      union { uint4 u4; short8 s8; } ah0, ah1, al0, al1;
      ah0.u4 = *(const uint4*)&klh[i0];
      ah1.u4 = *(const uint4*)&klh[i1];
      al0.u4 = *(const uint4*)&kll[i0];
      al1.u4 = *(const uint4*)&kll[i1];
      f32x4 dcur = (st == 0) ? Dst0 : Dst1;
      dcur = __builtin_amdgcn_mfma_f32_16x16x32_bf16(ah0.s8, qfh0.s8, dcur, 0, 0, 0);
      dcur = __builtin_amdgcn_mfma_f32_16x16x32_bf16(ah1.s8, qfh1.s8, dcur, 0, 0, 0);
      dcur = __builtin_amdgcn_mfma_f32_16x16x32_bf16(ah0.s8, qfl0.s8, dcur, 0, 0, 0);
      dcur = __builtin_amdgcn_mfma_f32_16x16x32_bf16(ah1.s8, qfl1.s8, dcur, 0, 0, 0);
      dcur = __builtin_amdgcn_mfma_f32_16x16x32_bf16(al0.s8, qfh0.s8, dcur, 0, 0, 0);
      dcur = __builtin_amdgcn_mfma_f32_16x16x32_bf16(al1.s8, qfh1.s8, dcur, 0, 0, 0);
      if (st == 0) Dst0 = dcur; else Dst1 = dcur;
    }

    // ---- e = exp(score); pack to bf16 pairs ----
    // Frag f, reg j at lane-group g' holds s_local = 16f + 4g' + j (col = r).
    float e0[4], e1[4];
#pragma unroll
    for (int j = 0; j < 4; ++j) { e0[j] = __expf(Dst0[j]); e1[j] = __expf(Dst1[j]); }
    uint_t p00 = pack2bf(e0[0], e0[1]), p01 = pack2bf(e0[2], e0[3]);
    uint_t p10 = pack2bf(e1[0], e1[1]), p11 = pack2bf(e1[2], e1[3]);

    // ---- redistribute into PV B-fragment: slot j -> s_local = 8g + j ----
    union { uint_t u[4]; short8 s8; } wf;
#pragma unroll
    for (int ii = 0; ii < 4; ++ii) {
      const int srcl = i + 16 * (2 * (g & 1) + (ii >> 1));
      const uint_t pe0 = (ii & 1) ? p01 : p00;
      const uint_t pe1 = (ii & 1) ? p11 : p10;
      const uint_t v0 = __shfl((int)pe0, srcl, 64);
      const uint_t v1 = __shfl((int)pe1, srcl, 64);
      wf.u[ii] = (g >= 2) ? v1 : v0;
    }

    // ---- O^T += V'^T x W_e : 5 d-subtiles (4 output + 1 Y/Z) ----
#pragma unroll
    for (int dt = 0; dt < 5; ++dt) {
      const int d = 16 * dt + i;
      union { uint4 u4; short8 s8; } av;
      av.u4 = *(const uint4*)&vt[d * 32 + 8 * (g ^ (d & 3))];
      f32x4 c = (dt == 0) ? accO0 : (dt == 1) ? accO1 : (dt == 2) ? accO2
                : (dt == 3) ? accO3 : accYZ;
      c = __builtin_amdgcn_mfma_f32_16x16x32_bf16(av.s8, wf.s8, c, 0, 0, 0);
      if (dt == 0) accO0 = c; else if (dt == 1) accO1 = c; else if (dt == 2) accO2 = c;
      else if (dt == 3) accO3 = c; else accYZ = c;
    }
  }

  // ---- epilogue: Y,Z broadcast; affinity renorm + gated residual ----
  const float Y = __shfl(accYZ[0], i, 64);   // row 64 -> lane i (g=0, reg 0)
  const float Z = __shfl(accYZ[1], i, 64);   // row 65 -> lane i (g=0, reg 1)
  const float a_r = ab[R];
  const float tt = a_r / Z;
  const float den = tt * Y + EPS_A;
  const float f = tt / den;
  const float g1 = 1.f - a_r;
  const float g2 = a_r * GAIN_F * f;

  const size_t rowoff = ((size_t)bu * V_DIM + R) * C_DIM + head * KQ_DIM;
#pragma unroll
  for (int dt = 0; dt < 4; ++dt) {
    const int d0 = 16 * dt + 4 * g;          // this lane's 4 consecutive dims
    const float4 x = *(const float4*)(vars + rowoff + d0);
    const f32x4 a = (dt == 0) ? accO0 : (dt == 1) ? accO1 : (dt == 2) ? accO2 : accO3;
    float4 o;
    o.x = g1 * x.x + g2 * a[0];
    o.y = g1 * x.y + g2 * a[1];
    o.z = g1 * x.z + g2 * a[2];
    o.w = g1 * x.w + g2 * a[3];
    *(float4*)(out + rowoff + d0) = o;
  }
}

// ---------------- kernel C: LN2 + modulated MLP + gating (in-place) -----
__global__ __launch_bounds__(256) void k_mlp(
    const float* __restrict__ aff,
    const float* __restrict__ ln2g, const float* __restrict__ ln2b,
    const float* __restrict__ m1W, const float* __restrict__ m1b,
    const float* __restrict__ m2W, const float* __restrict__ m2b,
    const float* __restrict__ s_all, float* __restrict__ io) {
  const int bid = blockIdx.x;
  const int row0 = bid * ROWS;
  const int bu = row0 / V_DIM;
  const int u = bu % U_DIM;
  const int t = threadIdx.x;

  __shared__ __align__(16) float xr[ROWS][C_DIM];
  __shared__ __align__(16) float xs2[ROWS][C_DIM];
  __shared__ float mean_s[ROWS], rstd_s[ROWS], a_row[ROWS];

  const float4* src = (const float4*)(io + (size_t)row0 * C_DIM);
  float4* xrf = (float4*)&xr[0][0];
#pragma unroll
  for (int i = 0; i < (ROWS * C_DIM) / 1024; ++i) xrf[i * 256 + t] = src[i * 256 + t];
  if (t < ROWS) a_row[t] = aff[row0 + t];
  __syncthreads();

  const int wave = t >> 6, lane = t & 63;
#pragma unroll
  for (int rr = 0; rr < ROWS / 4; ++rr) {
    const int r = wave * (ROWS / 4) + rr;
    float s1 = 0.f, s2 = 0.f;
#pragma unroll
    for (int i = 0; i < C_DIM / 64; ++i) { float x = xr[r][lane + 64 * i]; s1 += x; s2 += x * x; }
#pragma unroll
    for (int off = 32; off; off >>= 1) { s1 += __shfl_xor(s1, off); s2 += __shfl_xor(s2, off); }
    if (lane == 0) {
      float mm = s1 * (1.f / C_DIM);
      float var = s2 * (1.f / C_DIM) - mm * mm;
      mean_s[r] = mm; rstd_s[r] = rsqrtf(var + 1e-5f);
    }
  }
  __syncthreads();

  const float g = ln2g[t], bb = ln2b[t];
  const float sm1 = s_all[(3 * U_DIM + u) * C_DIM + t];
  const float sm2 = s_all[(4 * U_DIM + u) * C_DIM + t];
#pragma unroll
  for (int i = 0; i < ROWS; ++i) {
    float val = (xr[i][t] - mean_s[i]) * rstd_s[i] * g + bb;
    xs2[i][t] = val * sm1;
  }
  __syncthreads();

  float acc[ROWS];
#pragma unroll
  for (int i = 0; i < ROWS; ++i) acc[i] = 0.f;
  const float b1 = m1b[t];
#pragma unroll 2
  for (int c = 0; c < C_DIM; c += 4) {
    const float w0 = m1W[(c + 0) * C_DIM + t];
    const float w1 = m1W[(c + 1) * C_DIM + t];
    const float w2 = m1W[(c + 2) * C_DIM + t];
    const float w3 = m1W[(c + 3) * C_DIM + t];
#pragma unroll
    for (int r = 0; r < ROWS; ++r) {
      const float4 x4 = *(const float4*)&xs2[r][c];
      acc[r] = fmaf(x4.x, w0, fmaf(x4.y, w1, fmaf(x4.z, w2, fmaf(x4.w, w3, acc[r]))));
    }
  }
  __syncthreads();
#pragma unroll
  for (int r = 0; r < ROWS; ++r) {
    float x = acc[r] + b1;
    float ge = 0.5f * x * (1.f + erff(x * 0.70710678118f));
    xs2[r][t] = ge * sm2;
  }
  __syncthreads();

#pragma unroll
  for (int i = 0; i < ROWS; ++i) acc[i] = 0.f;
  const float b2 = m2b[t];
#pragma unroll 2
  for (int c = 0; c < C_DIM; c += 4) {
    const float w0 = m2W[(c + 0) * C_DIM + t];
    const float w1 = m2W[(c + 1) * C_DIM + t];
    const float w2 = m2W[(c + 2) * C_DIM + t];
    const float w3 = m2W[(c + 3) * C_DIM + t];
#pragma unroll
    for (int r = 0; r < ROWS; ++r) {
      const float4 x4 = *(const float4*)&xs2[r][c];
      acc[r] = fmaf(x4.x, w0, fmaf(x4.y, w1, fmaf(x4.z, w2, fmaf(x4.w, w3, acc[r]))));
    }
  }

  float* drow = io + (size_t)row0 * C_DIM;
#pragma unroll
  for (int r = 0; r < ROWS; ++r) {
    float x = acc[r] + b2;
    float ge = 0.5f * x * (1.f + erff(x * 0.70710678118f));
    const float a = a_row[r];
    drow[(size_t)r * C_DIM + t] = (1.f - a) * xr[r][t] + a * a * GAIN_F * ge;
  }
}

extern "C" void kernel_launch(void* const* d_in, const int* in_sizes, int n_in,
                              void* d_out, int out_size, void* d_ws, size_t ws_size,
                              hipStream_t stream) {
  const float* vars  = (const float*)d_in[0];
  const float* codes = (const float*)d_in[1];
  const float* aff   = (const float*)d_in[2];
  const float* ln1g  = (const float*)d_in[3];
  const float* ln1b  = (const float*)d_in[4];
  const float* ln2g  = (const float*)d_in[5];
  const float* ln2b  = (const float*)d_in[6];
  const float* qWc   = (const float*)d_in[7];
  const float* qW    = (const float*)d_in[8];
  const float* kWc   = (const float*)d_in[9];
  const float* kW    = (const float*)d_in[10];
  const float* vWc   = (const float*)d_in[11];
  const float* vW    = (const float*)d_in[12];
  const float* vb    = (const float*)d_in[13];
  const float* m1Wc  = (const float*)d_in[14];
  const float* m1W   = (const float*)d_in[15];
  const float* m1b   = (const float*)d_in[16];
  const float* m2Wc  = (const float*)d_in[17];
  const float* m2W   = (const float*)d_in[18];
  const float* m2b   = (const float*)d_in[19];
  float* out = (float*)d_out;

  const size_t headsz = (size_t)BUH * V_DIM * KQ_DIM;     // 4.19M elems
  const size_t s_all_sz = 5 * U_DIM * C_DIM;

  float* s_all = (float*)d_ws;
  ushort_t* qh = (ushort_t*)(s_all + s_all_sz);
  ushort_t* ql = qh + headsz;
  ushort_t* kh = ql + headsz;
  ushort_t* kl = kh + headsz;
  ushort_t* vo = kl + headsz;

  k_scales<<<5 * U_DIM, 256, 0, stream>>>(codes, qWc, kWc, vWc, m1Wc, m2Wc, s_all);
  k_qkv<<<(B_DIM * U_DIM * V_DIM) / ROWS, 256, 0, stream>>>(
      vars, ln1g, ln1b, qW, kW, vW, vb, s_all, qh, ql, kh, kl, vo);
  k_attn_mfma<<<8 * BUH, 512, 0, stream>>>(qh, ql, kh, kl, vo, aff, vars, out);
  k_mlp<<<(B_DIM * U_DIM * V_DIM) / ROWS, 256, 0, stream>>>(
      aff, ln2g, ln2b, m1W, m1b, m2W, m2b, s_all, out);
}

// Round 10
// 344.907 us; speedup vs baseline: 3.3174x; 1.2327x over previous
//
#include <hip/hip_runtime.h>
#include <math.h>

#define B_DIM 2
#define U_DIM 8
#define V_DIM 1024
#define C_DIM 256
#define H_DIM 4
#define KQ_DIM 64
#define CODE_DIM 192
#define EPS_A 1e-6f
#define GAIN_F 2.5f
#define GROWS 64
#define BUH (B_DIM * U_DIM * H_DIM)   // 64

typedef __attribute__((ext_vector_type(8))) short short8;
typedef __attribute__((ext_vector_type(4))) float f32x4;
typedef unsigned short ushort_t;
typedef unsigned int uint_t;

__device__ __forceinline__ ushort_t f2bf(float x) {
  union { float f; uint_t u; } v; v.f = x;
  uint_t r = v.u + 0x7FFFu + ((v.u >> 16) & 1u);   // round-nearest-even
  return (ushort_t)(r >> 16);
}
__device__ __forceinline__ float bf2f(ushort_t u) {
  union { uint_t u; float f; } v; v.u = ((uint_t)u) << 16; return v.f;
}
__device__ __forceinline__ uint_t pack2bf(float a, float b) {
  return (uint_t)f2bf(a) | ((uint_t)f2bf(b) << 16);
}
__device__ __forceinline__ float gelu_ex(float x) {
  return 0.5f * x * (1.f + erff(x * 0.70710678118f));
}

// ---------------- kernel 0: per-u modulation scales s[p][u][c] ----------
__global__ __launch_bounds__(256) void k_scales(
    const float* __restrict__ codes,
    const float* __restrict__ qWc, const float* __restrict__ kWc,
    const float* __restrict__ vWc, const float* __restrict__ m1Wc,
    const float* __restrict__ m2Wc, float* __restrict__ s_all) {
  int p = blockIdx.x / U_DIM;
  int u = blockIdx.x % U_DIM;
  const float* Wc = (p == 0) ? qWc : (p == 1) ? kWc : (p == 2) ? vWc
                    : (p == 3) ? m1Wc : m2Wc;
  __shared__ float cs[CODE_DIM];
  int t = threadIdx.x;
  if (t < CODE_DIM) cs[t] = codes[u * CODE_DIM + t];
  __syncthreads();
  float acc = 0.f;
  for (int j = 0; j < CODE_DIM; ++j) acc += cs[j] * Wc[j * C_DIM + t];
  s_all[(p * U_DIM + u) * C_DIM + t] = acc;
}

// ------- kernel W: weight prep — transpose to WT[n][c], split bf16 hi/lo
// wts slots (65536 ushorts each): p*2 = hi, p*2+1 = lo; p: 0=q,1=k,2=v,3=m1,4=m2
__global__ __launch_bounds__(256) void k_wprep(
    const float* __restrict__ qW, const float* __restrict__ kW,
    const float* __restrict__ vW, const float* __restrict__ m1W,
    const float* __restrict__ m2W, ushort_t* __restrict__ wts) {
  const int p = blockIdx.x / 16;
  const int tile = blockIdx.x % 16;
  const float* W = (p == 0) ? qW : (p == 1) ? kW : (p == 2) ? vW
                   : (p == 3) ? m1W : m2W;
  ushort_t* dh = wts + (size_t)(2 * p) * 65536;
  ushort_t* dl = wts + (size_t)(2 * p + 1) * 65536;
  const int cr0 = (tile >> 2) * 64;   // c (input-channel) block
  const int nc0 = (tile & 3) * 64;    // n (output-col) block
  __shared__ float ts[64][65];
  const int t = threadIdx.x;
  const int lr = t >> 6;              // 0..3
  const int lc = t & 63;
#pragma unroll
  for (int it = 0; it < 16; ++it) {
    const int r = it * 4 + lr;
    ts[r][lc] = W[(size_t)(cr0 + r) * C_DIM + nc0 + lc];
  }
  __syncthreads();
#pragma unroll
  for (int it = 0; it < 16; ++it) {
    const int r = it * 4 + lr;                // n within tile
    const float val = ts[lc][r];              // = W[cr0+lc][nc0+r]
    const ushort_t hh = f2bf(val);
    const size_t dst = (size_t)(nc0 + r) * C_DIM + cr0 + lc;
    dh[dst] = hh;
    dl[dst] = f2bf(val - bf2f(hh));
  }
}

// ------- kernel A: LN1 + modulated QKV projections via MFMA -------------
// block: 64 rows x 256 cols, 512 thr (8 waves). q/k 3-term hi/lo; v single.
__global__ __launch_bounds__(512) void k_qkv_mfma(
    const float* __restrict__ vars,
    const float* __restrict__ ln1g, const float* __restrict__ ln1b,
    const ushort_t* __restrict__ wts,
    const float* __restrict__ vbias, const float* __restrict__ s_all,
    ushort_t* __restrict__ qh_g, ushort_t* __restrict__ ql_g,
    ushort_t* __restrict__ kh_g, ushort_t* __restrict__ kl_g,
    ushort_t* __restrict__ vo_g) {
  const int bid = blockIdx.x;
  const int row0 = bid * GROWS;
  const int bu = row0 / V_DIM;
  const int u = bu % U_DIM;
  const int t = threadIdx.x;
  const int w = t >> 6, lane = t & 63, g = lane >> 4, i = lane & 15;

  __shared__ ushort_t xh[GROWS * C_DIM];   // 32 KB
  __shared__ ushort_t xl[GROWS * C_DIM];   // 32 KB
  __shared__ float mean_s[GROWS], rstd_s[GROWS];

  const int tr = t >> 3;                    // row, 8 threads/row
  const int tk0 = (t & 7) * 8;              // first col of 8-chunk
  float xbuf[32];
  {
    float s1 = 0.f, s2 = 0.f;
    const float* xrow = vars + (size_t)(row0 + tr) * C_DIM;
#pragma unroll
    for (int c = 0; c < 4; ++c) {
      const float4 a = *(const float4*)(xrow + tk0 + 64 * c);
      const float4 b = *(const float4*)(xrow + tk0 + 64 * c + 4);
      xbuf[c*8+0]=a.x; xbuf[c*8+1]=a.y; xbuf[c*8+2]=a.z; xbuf[c*8+3]=a.w;
      xbuf[c*8+4]=b.x; xbuf[c*8+5]=b.y; xbuf[c*8+6]=b.z; xbuf[c*8+7]=b.w;
      s1 += (a.x+a.y)+(a.z+a.w) + (b.x+b.y)+(b.z+b.w);
      s2 += a.x*a.x+a.y*a.y+a.z*a.z+a.w*a.w + b.x*b.x+b.y*b.y+b.z*b.z+b.w*b.w;
    }
#pragma unroll
    for (int off = 1; off < 8; off <<= 1) { s1 += __shfl_xor(s1, off); s2 += __shfl_xor(s2, off); }
    if ((t & 7) == 0) {
      const float mm = s1 * (1.f / C_DIM);
      const float var = s2 * (1.f / C_DIM) - mm * mm;
      mean_s[tr] = mm; rstd_s[tr] = rsqrtf(var + 1e-5f);
    }
  }
  __syncthreads();
  {
    const float mm = mean_s[tr], rs = rstd_s[tr];
#pragma unroll
    for (int c = 0; c < 4; ++c) {
      const float4 ga = *(const float4*)(ln1g + tk0 + 64 * c);
      const float4 gb = *(const float4*)(ln1g + tk0 + 64 * c + 4);
      const float4 ba = *(const float4*)(ln1b + tk0 + 64 * c);
      const float4 bb = *(const float4*)(ln1b + tk0 + 64 * c + 4);
      xbuf[c*8+0] = (xbuf[c*8+0]-mm)*rs*ga.x + ba.x;
      xbuf[c*8+1] = (xbuf[c*8+1]-mm)*rs*ga.y + ba.y;
      xbuf[c*8+2] = (xbuf[c*8+2]-mm)*rs*ga.z + ba.z;
      xbuf[c*8+3] = (xbuf[c*8+3]-mm)*rs*ga.w + ba.w;
      xbuf[c*8+4] = (xbuf[c*8+4]-mm)*rs*gb.x + bb.x;
      xbuf[c*8+5] = (xbuf[c*8+5]-mm)*rs*gb.y + bb.y;
      xbuf[c*8+6] = (xbuf[c*8+6]-mm)*rs*gb.z + bb.z;
      xbuf[c*8+7] = (xbuf[c*8+7]-mm)*rs*gb.w + bb.w;
    }
  }

  const int mrow = (w & 3) * 16 + i;
  const int swz = (mrow & 7) << 3;
  const int nbase = (w >> 2) * 128;

  for (int p = 0; p < 3; ++p) {
    if (p) __syncthreads();       // previous pass's LDS reads complete
    // ---- stage modulated x as hi/lo bf16, XOR-swizzled ----
    {
      const float* sp = s_all + (p * U_DIM + u) * C_DIM;
#pragma unroll
      for (int c = 0; c < 4; ++c) {
        const int k8 = tk0 + 64 * c;
        const float4 sa = *(const float4*)(sp + k8);
        const float4 sb = *(const float4*)(sp + k8 + 4);
        const float v0 = xbuf[c*8+0]*sa.x, v1 = xbuf[c*8+1]*sa.y;
        const float v2 = xbuf[c*8+2]*sa.z, v3 = xbuf[c*8+3]*sa.w;
        const float v4 = xbuf[c*8+4]*sb.x, v5 = xbuf[c*8+5]*sb.y;
        const float v6 = xbuf[c*8+6]*sb.z, v7 = xbuf[c*8+7]*sb.w;
        const ushort_t h0=f2bf(v0),h1=f2bf(v1),h2=f2bf(v2),h3=f2bf(v3);
        const ushort_t h4=f2bf(v4),h5=f2bf(v5),h6=f2bf(v6),h7=f2bf(v7);
        uint4 ph, pl;
        ph.x=(uint_t)h0|((uint_t)h1<<16); ph.y=(uint_t)h2|((uint_t)h3<<16);
        ph.z=(uint_t)h4|((uint_t)h5<<16); ph.w=(uint_t)h6|((uint_t)h7<<16);
        pl.x=(uint_t)f2bf(v0-bf2f(h0))|((uint_t)f2bf(v1-bf2f(h1))<<16);
        pl.y=(uint_t)f2bf(v2-bf2f(h2))|((uint_t)f2bf(v3-bf2f(h3))<<16);
        pl.z=(uint_t)f2bf(v4-bf2f(h4))|((uint_t)f2bf(v5-bf2f(h5))<<16);
        pl.w=(uint_t)f2bf(v6-bf2f(h6))|((uint_t)f2bf(v7-bf2f(h7))<<16);
        const int dst = tr * C_DIM + (k8 ^ ((tr & 7) << 3));
        *(uint4*)&xh[dst] = ph;
        *(uint4*)&xl[dst] = pl;
      }
    }
    __syncthreads();

    const ushort_t* WTh = wts + (size_t)(2 * p) * 65536;
    const ushort_t* WTl = wts + (size_t)(2 * p + 1) * 65536;
#pragma unroll 1
    for (int nt = 0; nt < 8; ++nt) {
      const int nrow = nbase + nt * 16 + i;
      const ushort_t* wr_h = WTh + (size_t)nrow * C_DIM;
      const ushort_t* wr_l = WTl + (size_t)nrow * C_DIM;
      f32x4 acc = {0.f, 0.f, 0.f, 0.f};
#pragma unroll
      for (int kc = 0; kc < 8; ++kc) {
        const int k0 = kc * 32 + 8 * g;
        union { uint4 u4; short8 s8; } afh, bfh;
        afh.u4 = *(const uint4*)(wr_h + k0);
        bfh.u4 = *(const uint4*)&xh[mrow * C_DIM + (k0 ^ swz)];
        acc = __builtin_amdgcn_mfma_f32_16x16x32_bf16(afh.s8, bfh.s8, acc, 0, 0, 0);
        if (p < 2) {
          union { uint4 u4; short8 s8; } afl, bfl;
          afl.u4 = *(const uint4*)(wr_l + k0);
          bfl.u4 = *(const uint4*)&xl[mrow * C_DIM + (k0 ^ swz)];
          acc = __builtin_amdgcn_mfma_f32_16x16x32_bf16(afl.s8, bfh.s8, acc, 0, 0, 0);
          acc = __builtin_amdgcn_mfma_f32_16x16x32_bf16(afh.s8, bfl.s8, acc, 0, 0, 0);
        }
      }
      // epilogue: lane holds O[m=row0+mrow][n0..n0+3]
      const int n0 = nbase + nt * 16 + 4 * g;
      const int hd = n0 >> 6, ch = n0 & 63;
      const int R = row0 + mrow;
      const size_t base = (((size_t)bu * H_DIM + hd) * V_DIM + (R % V_DIM)) * KQ_DIM + ch;
      if (p < 2) {
        ushort_t* dh = (p == 0) ? qh_g : kh_g;
        ushort_t* dl = (p == 0) ? ql_g : kl_g;
        const ushort_t a0 = f2bf(acc[0]), a1 = f2bf(acc[1]);
        const ushort_t a2 = f2bf(acc[2]), a3 = f2bf(acc[3]);
        uint2 sh, sl;
        sh.x = (uint_t)a0 | ((uint_t)a1 << 16);
        sh.y = (uint_t)a2 | ((uint_t)a3 << 16);
        sl.x = (uint_t)f2bf(acc[0]-bf2f(a0)) | ((uint_t)f2bf(acc[1]-bf2f(a1)) << 16);
        sl.y = (uint_t)f2bf(acc[2]-bf2f(a2)) | ((uint_t)f2bf(acc[3]-bf2f(a3)) << 16);
        *(uint2*)(dh + base) = sh;
        *(uint2*)(dl + base) = sl;
      } else {
        const float4 vb4 = *(const float4*)(vbias + n0);
        uint2 sv;
        sv.x = pack2bf(acc[0] + vb4.x, acc[1] + vb4.y);
        sv.y = pack2bf(acc[2] + vb4.z, acc[3] + vb4.w);
        *(uint2*)(vo_g + base) = sv;
      }
    }
  }
}

// ------- kernel B: fused MFMA attention (hi/lo QK; folded a/Y/Z) --------
__global__ __launch_bounds__(512) void k_attn_mfma(
    const ushort_t* __restrict__ qh, const ushort_t* __restrict__ ql,
    const ushort_t* __restrict__ kh, const ushort_t* __restrict__ kl,
    const ushort_t* __restrict__ v, const float* __restrict__ aff,
    const float* __restrict__ vars, float* __restrict__ out) {
  const int bid = blockIdx.x;
  const int buh = bid & 63;
  const int rb = bid >> 6;            // 0..7, 128 rows each
  const int bu = buh >> 2;
  const int head = buh & 3;
  const int t = threadIdx.x;
  const int w = t >> 6;               // wave 0..7
  const int lane = t & 63;
  const int g = lane >> 4;            // lane group 0..3
  const int i = lane & 15;

  const ushort_t* qhb = qh + (size_t)buh * V_DIM * KQ_DIM;
  const ushort_t* qlb = ql + (size_t)buh * V_DIM * KQ_DIM;
  const ushort_t* khb = kh + (size_t)buh * V_DIM * KQ_DIM;
  const ushort_t* klb = kl + (size_t)buh * V_DIM * KQ_DIM;
  const ushort_t* vb  = v  + (size_t)buh * V_DIM * KQ_DIM;
  const float* ab = aff + (size_t)bu * V_DIM;

  __shared__ ushort_t klh[32 * 64];
  __shared__ ushort_t kll[32 * 64];
  __shared__ ushort_t vt[80 * 32];

  const int R = rb * 128 + w * 16 + i;

  union { uint4 u4; short8 s8; } qfh0, qfh1, qfl0, qfl1;
  qfh0.u4 = *(const uint4*)(qhb + (size_t)R * 64 + 0 * 32 + 8 * g);
  qfh1.u4 = *(const uint4*)(qhb + (size_t)R * 64 + 1 * 32 + 8 * g);
  qfl0.u4 = *(const uint4*)(qlb + (size_t)R * 64 + 0 * 32 + 8 * g);
  qfl1.u4 = *(const uint4*)(qlb + (size_t)R * 64 + 1 * 32 + 8 * g);

  f32x4 accO0 = {0.f,0.f,0.f,0.f}, accO1 = {0.f,0.f,0.f,0.f};
  f32x4 accO2 = {0.f,0.f,0.f,0.f}, accO3 = {0.f,0.f,0.f,0.f};
  f32x4 accYZ = {0.f,0.f,0.f,0.f};
  const f32x4 zf = {0.f,0.f,0.f,0.f};

  const int ks_s = t >> 4;
  const int ks_k = (t & 15) * 4;
  const int vs_s = t & 31;
  const int vs_d0 = (t >> 5) * 4;

  for (int tile = 0; tile < V_DIM / 32; ++tile) {
    const int s0 = tile * 32;
    __syncthreads();
    {
      const uint2 kvh = *(const uint2*)(khb + (size_t)(s0 + ks_s) * 64 + ks_k);
      const uint2 kvl = *(const uint2*)(klb + (size_t)(s0 + ks_s) * 64 + ks_k);
      const int dsti = ks_s * 64 + (ks_k ^ ((ks_s & 7) << 3));
      *(uint2*)&klh[dsti] = kvh;
      *(uint2*)&kll[dsti] = kvl;
    }
    {
      const float a_s = ab[s0 + vs_s];
      const uint2 vv = *(const uint2*)(vb + (size_t)(s0 + vs_s) * 64 + vs_d0);
      const ushort_t* ve = (const ushort_t*)&vv;
#pragma unroll
      for (int qq = 0; qq < 4; ++qq) {
        const int d = vs_d0 + qq;
        vt[d * 32 + (vs_s ^ (8 * (d & 3)))] = f2bf(a_s * bf2f(ve[qq]));
      }
      if (t < 32) {
        vt[64 * 32 + (vs_s ^ 0)] = f2bf(a_s);
        vt[65 * 32 + (vs_s ^ 8)] = 0x3F80u;
      }
    }
    __syncthreads();

    f32x4 Dst0 = zf, Dst1 = zf;
#pragma unroll
    for (int st = 0; st < 2; ++st) {
      const int srow = st * 16 + i;
      const int i0 = srow * 64 + ((0 * 32 + 8 * g) ^ ((srow & 7) << 3));
      const int i1 = srow * 64 + ((1 * 32 + 8 * g) ^ ((srow & 7) << 3));
      union { uint4 u4; short8 s8; } ah0, ah1, al0, al1;
      ah0.u4 = *(const uint4*)&klh[i0];
      ah1.u4 = *(const uint4*)&klh[i1];
      al0.u4 = *(const uint4*)&kll[i0];
      al1.u4 = *(const uint4*)&kll[i1];
      f32x4 dcur = (st == 0) ? Dst0 : Dst1;
      dcur = __builtin_amdgcn_mfma_f32_16x16x32_bf16(ah0.s8, qfh0.s8, dcur, 0, 0, 0);
      dcur = __builtin_amdgcn_mfma_f32_16x16x32_bf16(ah1.s8, qfh1.s8, dcur, 0, 0, 0);
      dcur = __builtin_amdgcn_mfma_f32_16x16x32_bf16(ah0.s8, qfl0.s8, dcur, 0, 0, 0);
      dcur = __builtin_amdgcn_mfma_f32_16x16x32_bf16(ah1.s8, qfl1.s8, dcur, 0, 0, 0);
      dcur = __builtin_amdgcn_mfma_f32_16x16x32_bf16(al0.s8, qfh0.s8, dcur, 0, 0, 0);
      dcur = __builtin_amdgcn_mfma_f32_16x16x32_bf16(al1.s8, qfh1.s8, dcur, 0, 0, 0);
      if (st == 0) Dst0 = dcur; else Dst1 = dcur;
    }

    float e0[4], e1[4];
#pragma unroll
    for (int j = 0; j < 4; ++j) { e0[j] = __expf(Dst0[j]); e1[j] = __expf(Dst1[j]); }
    uint_t p00 = pack2bf(e0[0], e0[1]), p01 = pack2bf(e0[2], e0[3]);
    uint_t p10 = pack2bf(e1[0], e1[1]), p11 = pack2bf(e1[2], e1[3]);

    union { uint_t u[4]; short8 s8; } wf;
#pragma unroll
    for (int ii = 0; ii < 4; ++ii) {
      const int srcl = i + 16 * (2 * (g & 1) + (ii >> 1));
      const uint_t pe0 = (ii & 1) ? p01 : p00;
      const uint_t pe1 = (ii & 1) ? p11 : p10;
      const uint_t v0 = __shfl((int)pe0, srcl, 64);
      const uint_t v1 = __shfl((int)pe1, srcl, 64);
      wf.u[ii] = (g >= 2) ? v1 : v0;
    }

#pragma unroll
    for (int dt = 0; dt < 5; ++dt) {
      const int d = 16 * dt + i;
      union { uint4 u4; short8 s8; } av;
      av.u4 = *(const uint4*)&vt[d * 32 + 8 * (g ^ (d & 3))];
      f32x4 c = (dt == 0) ? accO0 : (dt == 1) ? accO1 : (dt == 2) ? accO2
                : (dt == 3) ? accO3 : accYZ;
      c = __builtin_amdgcn_mfma_f32_16x16x32_bf16(av.s8, wf.s8, c, 0, 0, 0);
      if (dt == 0) accO0 = c; else if (dt == 1) accO1 = c; else if (dt == 2) accO2 = c;
      else if (dt == 3) accO3 = c; else accYZ = c;
    }
  }

  const float Y = __shfl(accYZ[0], i, 64);
  const float Z = __shfl(accYZ[1], i, 64);
  const float a_r = ab[R];
  const float tt = a_r / Z;
  const float den = tt * Y + EPS_A;
  const float f = tt / den;
  const float g1 = 1.f - a_r;
  const float g2 = a_r * GAIN_F * f;

  const size_t rowoff = ((size_t)bu * V_DIM + R) * C_DIM + head * KQ_DIM;
#pragma unroll
  for (int dt = 0; dt < 4; ++dt) {
    const int d0 = 16 * dt + 4 * g;
    const float4 x = *(const float4*)(vars + rowoff + d0);
    const f32x4 a = (dt == 0) ? accO0 : (dt == 1) ? accO1 : (dt == 2) ? accO2 : accO3;
    float4 o;
    o.x = g1 * x.x + g2 * a[0];
    o.y = g1 * x.y + g2 * a[1];
    o.z = g1 * x.z + g2 * a[2];
    o.w = g1 * x.w + g2 * a[3];
    *(float4*)(out + rowoff + d0) = o;
  }
}

// ------- kernel C: LN2 + MLP via MFMA (3-term), gated in-place ----------
__global__ __launch_bounds__(512) void k_mlp_mfma(
    const float* __restrict__ aff,
    const float* __restrict__ ln2g, const float* __restrict__ ln2b,
    const ushort_t* __restrict__ wts,
    const float* __restrict__ m1bias, const float* __restrict__ m2bias,
    const float* __restrict__ s_all, float* __restrict__ io) {
  const int bid = blockIdx.x;
  const int row0 = bid * GROWS;
  const int bu = row0 / V_DIM;
  const int u = bu % U_DIM;
  const int t = threadIdx.x;
  const int w = t >> 6, lane = t & 63, g = lane >> 4, i = lane & 15;

  __shared__ ushort_t bh[GROWS * C_DIM];   // x-stage, then h1-stage
  __shared__ ushort_t bl[GROWS * C_DIM];
  __shared__ float mean_s[GROWS], rstd_s[GROWS];

  const int tr = t >> 3;
  const int tk0 = (t & 7) * 8;
  float xbuf[32];
  {
    float s1 = 0.f, s2 = 0.f;
    const float* xrow = io + (size_t)(row0 + tr) * C_DIM;
#pragma unroll
    for (int c = 0; c < 4; ++c) {
      const float4 a = *(const float4*)(xrow + tk0 + 64 * c);
      const float4 b = *(const float4*)(xrow + tk0 + 64 * c + 4);
      xbuf[c*8+0]=a.x; xbuf[c*8+1]=a.y; xbuf[c*8+2]=a.z; xbuf[c*8+3]=a.w;
      xbuf[c*8+4]=b.x; xbuf[c*8+5]=b.y; xbuf[c*8+6]=b.z; xbuf[c*8+7]=b.w;
      s1 += (a.x+a.y)+(a.z+a.w) + (b.x+b.y)+(b.z+b.w);
      s2 += a.x*a.x+a.y*a.y+a.z*a.z+a.w*a.w + b.x*b.x+b.y*b.y+b.z*b.z+b.w*b.w;
    }
#pragma unroll
    for (int off = 1; off < 8; off <<= 1) { s1 += __shfl_xor(s1, off); s2 += __shfl_xor(s2, off); }
    if ((t & 7) == 0) {
      const float mm = s1 * (1.f / C_DIM);
      const float var = s2 * (1.f / C_DIM) - mm * mm;
      mean_s[tr] = mm; rstd_s[tr] = rsqrtf(var + 1e-5f);
    }
  }
  __syncthreads();
  {
    const float mm = mean_s[tr], rs = rstd_s[tr];
    const float* sp = s_all + (3 * U_DIM + u) * C_DIM;
#pragma unroll
    for (int c = 0; c < 4; ++c) {
      const int k8 = tk0 + 64 * c;
      const float4 ga = *(const float4*)(ln2g + k8);
      const float4 gb = *(const float4*)(ln2g + k8 + 4);
      const float4 ba = *(const float4*)(ln2b + k8);
      const float4 bb = *(const float4*)(ln2b + k8 + 4);
      const float4 sa = *(const float4*)(sp + k8);
      const float4 sb = *(const float4*)(sp + k8 + 4);
      const float v0 = ((xbuf[c*8+0]-mm)*rs*ga.x + ba.x) * sa.x;
      const float v1 = ((xbuf[c*8+1]-mm)*rs*ga.y + ba.y) * sa.y;
      const float v2 = ((xbuf[c*8+2]-mm)*rs*ga.z + ba.z) * sa.z;
      const float v3 = ((xbuf[c*8+3]-mm)*rs*ga.w + ba.w) * sa.w;
      const float v4 = ((xbuf[c*8+4]-mm)*rs*gb.x + bb.x) * sb.x;
      const float v5 = ((xbuf[c*8+5]-mm)*rs*gb.y + bb.y) * sb.y;
      const float v6 = ((xbuf[c*8+6]-mm)*rs*gb.z + bb.z) * sb.z;
      const float v7 = ((xbuf[c*8+7]-mm)*rs*gb.w + bb.w) * sb.w;
      const ushort_t h0=f2bf(v0),h1=f2bf(v1),h2=f2bf(v2),h3=f2bf(v3);
      const ushort_t h4=f2bf(v4),h5=f2bf(v5),h6=f2bf(v6),h7=f2bf(v7);
      uint4 ph, pl;
      ph.x=(uint_t)h0|((uint_t)h1<<16); ph.y=(uint_t)h2|((uint_t)h3<<16);
      ph.z=(uint_t)h4|((uint_t)h5<<16); ph.w=(uint_t)h6|((uint_t)h7<<16);
      pl.x=(uint_t)f2bf(v0-bf2f(h0))|((uint_t)f2bf(v1-bf2f(h1))<<16);
      pl.y=(uint_t)f2bf(v2-bf2f(h2))|((uint_t)f2bf(v3-bf2f(h3))<<16);
      pl.z=(uint_t)f2bf(v4-bf2f(h4))|((uint_t)f2bf(v5-bf2f(h5))<<16);
      pl.w=(uint_t)f2bf(v6-bf2f(h6))|((uint_t)f2bf(v7-bf2f(h7))<<16);
      const int dst = tr * C_DIM + (k8 ^ ((tr & 7) << 3));
      *(uint4*)&bh[dst] = ph;
      *(uint4*)&bl[dst] = pl;
    }
  }
  __syncthreads();

  const int mrow = (w & 3) * 16 + i;
  const int swz = (mrow & 7) << 3;
  const int nbase = (w >> 2) * 128;

  // ---- GEMM1: h1 = x @ m1W (3-term), all 8 tiles kept ----
  const ushort_t* W1h = wts + (size_t)6 * 65536;
  const ushort_t* W1l = wts + (size_t)7 * 65536;
  f32x4 acc1[8];
#pragma unroll
  for (int nt = 0; nt < 8; ++nt) {
    const int nrow = nbase + nt * 16 + i;
    const ushort_t* wr_h = W1h + (size_t)nrow * C_DIM;
    const ushort_t* wr_l = W1l + (size_t)nrow * C_DIM;
    f32x4 acc = {0.f, 0.f, 0.f, 0.f};
#pragma unroll
    for (int kc = 0; kc < 8; ++kc) {
      const int k0 = kc * 32 + 8 * g;
      union { uint4 u4; short8 s8; } afh, afl, bfh, bfl;
      afh.u4 = *(const uint4*)(wr_h + k0);
      afl.u4 = *(const uint4*)(wr_l + k0);
      bfh.u4 = *(const uint4*)&bh[mrow * C_DIM + (k0 ^ swz)];
      bfl.u4 = *(const uint4*)&bl[mrow * C_DIM + (k0 ^ swz)];
      acc = __builtin_amdgcn_mfma_f32_16x16x32_bf16(afh.s8, bfh.s8, acc, 0, 0, 0);
      acc = __builtin_amdgcn_mfma_f32_16x16x32_bf16(afl.s8, bfh.s8, acc, 0, 0, 0);
      acc = __builtin_amdgcn_mfma_f32_16x16x32_bf16(afh.s8, bfl.s8, acc, 0, 0, 0);
    }
    acc1[nt] = acc;
  }
  __syncthreads();   // all reads of bh/bl done — safe to overwrite with h1

  // ---- stage h1 = gelu(y1 + b1) * sm2, hi/lo ----
  {
    const float* s2p = s_all + (4 * U_DIM + u) * C_DIM;
#pragma unroll
    for (int nt = 0; nt < 8; ++nt) {
      const int n0 = nbase + nt * 16 + 4 * g;
      const float4 b4 = *(const float4*)(m1bias + n0);
      const float4 s4 = *(const float4*)(s2p + n0);
      const float v0 = gelu_ex(acc1[nt][0] + b4.x) * s4.x;
      const float v1 = gelu_ex(acc1[nt][1] + b4.y) * s4.y;
      const float v2 = gelu_ex(acc1[nt][2] + b4.z) * s4.z;
      const float v3 = gelu_ex(acc1[nt][3] + b4.w) * s4.w;
      const ushort_t h0=f2bf(v0),h1=f2bf(v1),h2=f2bf(v2),h3=f2bf(v3);
      uint2 ph, pl;
      ph.x=(uint_t)h0|((uint_t)h1<<16); ph.y=(uint_t)h2|((uint_t)h3<<16);
      pl.x=(uint_t)f2bf(v0-bf2f(h0))|((uint_t)f2bf(v1-bf2f(h1))<<16);
      pl.y=(uint_t)f2bf(v2-bf2f(h2))|((uint_t)f2bf(v3-bf2f(h3))<<16);
      const int dst = mrow * C_DIM + (n0 ^ swz);
      *(uint2*)&bh[dst] = ph;
      *(uint2*)&bl[dst] = pl;
    }
  }
  __syncthreads();

  // ---- GEMM2 + epilogue ----
  const ushort_t* W2h = wts + (size_t)8 * 65536;
  const ushort_t* W2l = wts + (size_t)9 * 65536;
  const int R = row0 + mrow;
  const float a_r = aff[R];
  const float ga = 1.f - a_r;
  const float gg = a_r * a_r * GAIN_F;
#pragma unroll 1
  for (int nt = 0; nt < 8; ++nt) {
    const int nrow = nbase + nt * 16 + i;
    const ushort_t* wr_h = W2h + (size_t)nrow * C_DIM;
    const ushort_t* wr_l = W2l + (size_t)nrow * C_DIM;
    f32x4 acc = {0.f, 0.f, 0.f, 0.f};
#pragma unroll
    for (int kc = 0; kc < 8; ++kc) {
      const int k0 = kc * 32 + 8 * g;
      union { uint4 u4; short8 s8; } afh, afl, bfh, bfl;
      afh.u4 = *(const uint4*)(wr_h + k0);
      afl.u4 = *(const uint4*)(wr_l + k0);
      bfh.u4 = *(const uint4*)&bh[mrow * C_DIM + (k0 ^ swz)];
      bfl.u4 = *(const uint4*)&bl[mrow * C_DIM + (k0 ^ swz)];
      acc = __builtin_amdgcn_mfma_f32_16x16x32_bf16(afh.s8, bfh.s8, acc, 0, 0, 0);
      acc = __builtin_amdgcn_mfma_f32_16x16x32_bf16(afl.s8, bfh.s8, acc, 0, 0, 0);
      acc = __builtin_amdgcn_mfma_f32_16x16x32_bf16(afh.s8, bfl.s8, acc, 0, 0, 0);
    }
    const int n0 = nbase + nt * 16 + 4 * g;
    const float4 b4 = *(const float4*)(m2bias + n0);
    const float e0 = gelu_ex(acc[0] + b4.x);
    const float e1 = gelu_ex(acc[1] + b4.y);
    const float e2 = gelu_ex(acc[2] + b4.z);
    const float e3 = gelu_ex(acc[3] + b4.w);
    float* orow = io + (size_t)R * C_DIM + n0;
    const float4 xr = *(const float4*)orow;
    float4 o;
    o.x = ga * xr.x + gg * e0;
    o.y = ga * xr.y + gg * e1;
    o.z = ga * xr.z + gg * e2;
    o.w = ga * xr.w + gg * e3;
    *(float4*)orow = o;
  }
}

extern "C" void kernel_launch(void* const* d_in, const int* in_sizes, int n_in,
                              void* d_out, int out_size, void* d_ws, size_t ws_size,
                              hipStream_t stream) {
  const float* vars  = (const float*)d_in[0];
  const float* codes = (const float*)d_in[1];
  const float* aff   = (const float*)d_in[2];
  const float* ln1g  = (const float*)d_in[3];
  const float* ln1b  = (const float*)d_in[4];
  const float* ln2g  = (const float*)d_in[5];
  const float* ln2b  = (const float*)d_in[6];
  const float* qWc   = (const float*)d_in[7];
  const float* qW    = (const float*)d_in[8];
  const float* kWc   = (const float*)d_in[9];
  const float* kW    = (const float*)d_in[10];
  const float* vWc   = (const float*)d_in[11];
  const float* vW    = (const float*)d_in[12];
  const float* vb    = (const float*)d_in[13];
  const float* m1Wc  = (const float*)d_in[14];
  const float* m1W   = (const float*)d_in[15];
  const float* m1b   = (const float*)d_in[16];
  const float* m2Wc  = (const float*)d_in[17];
  const float* m2W   = (const float*)d_in[18];
  const float* m2b   = (const float*)d_in[19];
  float* out = (float*)d_out;

  const size_t headsz = (size_t)BUH * V_DIM * KQ_DIM;     // 4.19M elems
  const size_t s_all_sz = 5 * U_DIM * C_DIM;              // 10240 floats

  float* s_all = (float*)d_ws;
  ushort_t* wts = (ushort_t*)(s_all + s_all_sz);          // 10*65536 ushorts
  ushort_t* qh = wts + (size_t)10 * 65536;
  ushort_t* ql = qh + headsz;
  ushort_t* kh = ql + headsz;
  ushort_t* kl = kh + headsz;
  ushort_t* vo = kl + headsz;

  k_wprep<<<80, 256, 0, stream>>>(qW, kW, vW, m1W, m2W, wts);
  k_scales<<<5 * U_DIM, 256, 0, stream>>>(codes, qWc, kWc, vWc, m1Wc, m2Wc, s_all);
  k_qkv_mfma<<<(B_DIM * U_DIM * V_DIM) / GROWS, 512, 0, stream>>>(
      vars, ln1g, ln1b, wts, vb, s_all, qh, ql, kh, kl, vo);
  k_attn_mfma<<<8 * BUH, 512, 0, stream>>>(qh, ql, kh, kl, vo, aff, vars, out);
  k_mlp_mfma<<<(B_DIM * U_DIM * V_DIM) / GROWS, 512, 0, stream>>>(
      aff, ln2g, ln2b, wts, m1b, m2b, s_all, out);
}

// Round 13
// 321.839 us; speedup vs baseline: 3.5551x; 1.0717x over previous
//
#include <hip/hip_runtime.h>
#include <math.h>

#define B_DIM 2
#define U_DIM 8
#define V_DIM 1024
#define C_DIM 256
#define H_DIM 4
#define KQ_DIM 64
#define CODE_DIM 192
#define EPS_A 1e-6f
#define GAIN_F 2.5f
#define GROWS 32
#define BUH (B_DIM * U_DIM * H_DIM)   // 64

typedef __attribute__((ext_vector_type(8))) short short8;
typedef __attribute__((ext_vector_type(4))) float f32x4;
typedef unsigned short ushort_t;
typedef unsigned int uint_t;

__device__ __forceinline__ ushort_t f2bf(float x) {
  union { float f; uint_t u; } v; v.f = x;
  uint_t r = v.u + 0x7FFFu + ((v.u >> 16) & 1u);   // round-nearest-even
  return (ushort_t)(r >> 16);
}
__device__ __forceinline__ float bf2f(ushort_t u) {
  union { uint_t u; float f; } v; v.u = ((uint_t)u) << 16; return v.f;
}
__device__ __forceinline__ uint_t pack2bf(float a, float b) {
  return (uint_t)f2bf(a) | ((uint_t)f2bf(b) << 16);
}
__device__ __forceinline__ float gelu_ex(float x) {
  return 0.5f * x * (1.f + erff(x * 0.70710678118f));
}

// ---------------- kernel 0: per-u modulation scales s[p][u][c] ----------
__global__ __launch_bounds__(256) void k_scales(
    const float* __restrict__ codes,
    const float* __restrict__ qWc, const float* __restrict__ kWc,
    const float* __restrict__ vWc, const float* __restrict__ m1Wc,
    const float* __restrict__ m2Wc, float* __restrict__ s_all) {
  int p = blockIdx.x / U_DIM;
  int u = blockIdx.x % U_DIM;
  const float* Wc = (p == 0) ? qWc : (p == 1) ? kWc : (p == 2) ? vWc
                    : (p == 3) ? m1Wc : m2Wc;
  __shared__ float cs[CODE_DIM];
  int t = threadIdx.x;
  if (t < CODE_DIM) cs[t] = codes[u * CODE_DIM + t];
  __syncthreads();
  float acc = 0.f;
  for (int j = 0; j < CODE_DIM; ++j) acc += cs[j] * Wc[j * C_DIM + t];
  s_all[(p * U_DIM + u) * C_DIM + t] = acc;
}

// ------- kernel W: weight prep — transpose to WT[n][c], split bf16 hi/lo
__global__ __launch_bounds__(256) void k_wprep(
    const float* __restrict__ qW, const float* __restrict__ kW,
    const float* __restrict__ vW, const float* __restrict__ m1W,
    const float* __restrict__ m2W, ushort_t* __restrict__ wts) {
  const int p = blockIdx.x / 16;
  const int tile = blockIdx.x % 16;
  const float* W = (p == 0) ? qW : (p == 1) ? kW : (p == 2) ? vW
                   : (p == 3) ? m1W : m2W;
  ushort_t* dh = wts + (size_t)(2 * p) * 65536;
  ushort_t* dl = wts + (size_t)(2 * p + 1) * 65536;
  const int cr0 = (tile >> 2) * 64;   // c (input-channel) block
  const int nc0 = (tile & 3) * 64;    // n (output-col) block
  __shared__ float ts[64][65];
  const int t = threadIdx.x;
  const int lr = t >> 6;              // 0..3
  const int lc = t & 63;
#pragma unroll
  for (int it = 0; it < 16; ++it) {
    const int r = it * 4 + lr;
    ts[r][lc] = W[(size_t)(cr0 + r) * C_DIM + nc0 + lc];
  }
  __syncthreads();
#pragma unroll
  for (int it = 0; it < 16; ++it) {
    const int r = it * 4 + lr;                // n within tile
    const float val = ts[lc][r];              // = W[cr0+lc][nc0+r]
    const ushort_t hh = f2bf(val);
    const size_t dst = (size_t)(nc0 + r) * C_DIM + cr0 + lc;
    dh[dst] = hh;
    dl[dst] = f2bf(val - bf2f(hh));
  }
}

// ------- kernel A: LN1 + modulated QKV projections via MFMA -------------
// block: 32 rows x 256 cols, 512 thr (8 waves = 2 row-tiles x 4 col-groups)
__global__ __launch_bounds__(512) void k_qkv_mfma(
    const float* __restrict__ vars,
    const float* __restrict__ ln1g, const float* __restrict__ ln1b,
    const ushort_t* __restrict__ wts,
    const float* __restrict__ vbias, const float* __restrict__ s_all,
    ushort_t* __restrict__ qh_g, ushort_t* __restrict__ ql_g,
    ushort_t* __restrict__ kh_g, ushort_t* __restrict__ kl_g,
    ushort_t* __restrict__ vo_g) {
  const int bid = blockIdx.x;
  const int row0 = bid * GROWS;
  const int bu = row0 / V_DIM;
  const int u = bu % U_DIM;
  const int t = threadIdx.x;
  const int w = t >> 6, lane = t & 63, g = lane >> 4, i = lane & 15;

  __shared__ ushort_t xh[GROWS * C_DIM];   // 16 KB
  __shared__ ushort_t xl[GROWS * C_DIM];   // 16 KB
  __shared__ float mean_s[GROWS], rstd_s[GROWS];

  const int tr = t >> 4;                    // row, 16 threads/row
  const int tk0 = (t & 15) * 16;            // 16 contiguous elems per thread
  float xbuf[16];
  {
    float s1 = 0.f, s2 = 0.f;
    const float* xrow = vars + (size_t)(row0 + tr) * C_DIM + tk0;
#pragma unroll
    for (int c = 0; c < 4; ++c) {
      const float4 a = *(const float4*)(xrow + 4 * c);
      xbuf[c*4+0]=a.x; xbuf[c*4+1]=a.y; xbuf[c*4+2]=a.z; xbuf[c*4+3]=a.w;
      s1 += (a.x+a.y)+(a.z+a.w);
      s2 += a.x*a.x+a.y*a.y+a.z*a.z+a.w*a.w;
    }
#pragma unroll
    for (int off = 1; off < 16; off <<= 1) { s1 += __shfl_xor(s1, off); s2 += __shfl_xor(s2, off); }
    if ((t & 15) == 0) {
      const float mm = s1 * (1.f / C_DIM);
      const float var = s2 * (1.f / C_DIM) - mm * mm;
      mean_s[tr] = mm; rstd_s[tr] = rsqrtf(var + 1e-5f);
    }
  }
  __syncthreads();
  {
    const float mm = mean_s[tr], rs = rstd_s[tr];
#pragma unroll
    for (int c = 0; c < 4; ++c) {
      const float4 ga = *(const float4*)(ln1g + tk0 + 4 * c);
      const float4 ba = *(const float4*)(ln1b + tk0 + 4 * c);
      xbuf[c*4+0] = (xbuf[c*4+0]-mm)*rs*ga.x + ba.x;
      xbuf[c*4+1] = (xbuf[c*4+1]-mm)*rs*ga.y + ba.y;
      xbuf[c*4+2] = (xbuf[c*4+2]-mm)*rs*ga.z + ba.z;
      xbuf[c*4+3] = (xbuf[c*4+3]-mm)*rs*ga.w + ba.w;
    }
  }

  const int mrow = (w & 1) * 16 + i;        // row tile
  const int swz = (mrow & 7) << 3;
  const int nbase = (w >> 1) * 64;          // col group (4 groups x 64)

  for (int p = 0; p < 3; ++p) {
    if (p) __syncthreads();       // previous pass's LDS reads complete
    // ---- stage modulated x as hi/lo bf16, XOR-swizzled ----
    {
      const float* sp = s_all + (p * U_DIM + u) * C_DIM + tk0;
#pragma unroll
      for (int h = 0; h < 2; ++h) {   // two 8-elem chunks
        const float4 sa = *(const float4*)(sp + 8 * h);
        const float4 sb = *(const float4*)(sp + 8 * h + 4);
        const float v0 = xbuf[8*h+0]*sa.x, v1 = xbuf[8*h+1]*sa.y;
        const float v2 = xbuf[8*h+2]*sa.z, v3 = xbuf[8*h+3]*sa.w;
        const float v4 = xbuf[8*h+4]*sb.x, v5 = xbuf[8*h+5]*sb.y;
        const float v6 = xbuf[8*h+6]*sb.z, v7 = xbuf[8*h+7]*sb.w;
        const ushort_t h0=f2bf(v0),h1=f2bf(v1),h2=f2bf(v2),h3=f2bf(v3);
        const ushort_t h4=f2bf(v4),h5=f2bf(v5),h6=f2bf(v6),h7=f2bf(v7);
        uint4 ph, pl;
        ph.x=(uint_t)h0|((uint_t)h1<<16); ph.y=(uint_t)h2|((uint_t)h3<<16);
        ph.z=(uint_t)h4|((uint_t)h5<<16); ph.w=(uint_t)h6|((uint_t)h7<<16);
        pl.x=(uint_t)f2bf(v0-bf2f(h0))|((uint_t)f2bf(v1-bf2f(h1))<<16);
        pl.y=(uint_t)f2bf(v2-bf2f(h2))|((uint_t)f2bf(v3-bf2f(h3))<<16);
        pl.z=(uint_t)f2bf(v4-bf2f(h4))|((uint_t)f2bf(v5-bf2f(h5))<<16);
        pl.w=(uint_t)f2bf(v6-bf2f(h6))|((uint_t)f2bf(v7-bf2f(h7))<<16);
        const int dst = tr * C_DIM + ((tk0 + 8 * h) ^ ((tr & 7) << 3));
        *(uint4*)&xh[dst] = ph;
        *(uint4*)&xl[dst] = pl;
      }
    }
    __syncthreads();

    const ushort_t* WTh = wts + (size_t)(2 * p) * 65536;
    const ushort_t* WTl = wts + (size_t)(2 * p + 1) * 65536;
#pragma unroll 2
    for (int nt = 0; nt < 4; ++nt) {
      const int nrow = nbase + nt * 16 + i;
      const ushort_t* wr_h = WTh + (size_t)nrow * C_DIM;
      const ushort_t* wr_l = WTl + (size_t)nrow * C_DIM;
      f32x4 acc = {0.f, 0.f, 0.f, 0.f};
#pragma unroll
      for (int kc = 0; kc < 8; ++kc) {
        const int k0 = kc * 32 + 8 * g;
        union { uint4 u4; short8 s8; } afh, bfh;
        afh.u4 = *(const uint4*)(wr_h + k0);
        bfh.u4 = *(const uint4*)&xh[mrow * C_DIM + (k0 ^ swz)];
        acc = __builtin_amdgcn_mfma_f32_16x16x32_bf16(afh.s8, bfh.s8, acc, 0, 0, 0);
        if (p < 2) {
          union { uint4 u4; short8 s8; } afl, bfl;
          afl.u4 = *(const uint4*)(wr_l + k0);
          bfl.u4 = *(const uint4*)&xl[mrow * C_DIM + (k0 ^ swz)];
          acc = __builtin_amdgcn_mfma_f32_16x16x32_bf16(afl.s8, bfh.s8, acc, 0, 0, 0);
          acc = __builtin_amdgcn_mfma_f32_16x16x32_bf16(afh.s8, bfl.s8, acc, 0, 0, 0);
        }
      }
      // epilogue: lane holds O[m=row0+mrow][n0..n0+3]
      const int n0 = nbase + nt * 16 + 4 * g;
      const int hd = n0 >> 6, ch = n0 & 63;
      const int R = row0 + mrow;
      const size_t base = (((size_t)bu * H_DIM + hd) * V_DIM + (R % V_DIM)) * KQ_DIM + ch;
      if (p < 2) {
        ushort_t* dh = (p == 0) ? qh_g : kh_g;
        ushort_t* dl = (p == 0) ? ql_g : kl_g;
        const ushort_t a0 = f2bf(acc[0]), a1 = f2bf(acc[1]);
        const ushort_t a2 = f2bf(acc[2]), a3 = f2bf(acc[3]);
        uint2 sh, sl;
        sh.x = (uint_t)a0 | ((uint_t)a1 << 16);
        sh.y = (uint_t)a2 | ((uint_t)a3 << 16);
        sl.x = (uint_t)f2bf(acc[0]-bf2f(a0)) | ((uint_t)f2bf(acc[1]-bf2f(a1)) << 16);
        sl.y = (uint_t)f2bf(acc[2]-bf2f(a2)) | ((uint_t)f2bf(acc[3]-bf2f(a3)) << 16);
        *(uint2*)(dh + base) = sh;
        *(uint2*)(dl + base) = sl;
      } else {
        const float4 vb4 = *(const float4*)(vbias + n0);
        uint2 sv;
        sv.x = pack2bf(acc[0] + vb4.x, acc[1] + vb4.y);
        sv.y = pack2bf(acc[2] + vb4.z, acc[3] + vb4.w);
        *(uint2*)(vo_g + base) = sv;
      }
    }
  }
}

// ------- kernel B: fused MFMA attention (hi/lo QK; folded a/Y/Z) --------
__global__ __launch_bounds__(512) void k_attn_mfma(
    const ushort_t* __restrict__ qh, const ushort_t* __restrict__ ql,
    const ushort_t* __restrict__ kh, const ushort_t* __restrict__ kl,
    const ushort_t* __restrict__ v, const float* __restrict__ aff,
    const float* __restrict__ vars, float* __restrict__ out) {
  const int bid = blockIdx.x;
  const int buh = bid & 63;
  const int rb = bid >> 6;            // 0..7, 128 rows each
  const int bu = buh >> 2;
  const int head = buh & 3;
  const int t = threadIdx.x;
  const int w = t >> 6;               // wave 0..7
  const int lane = t & 63;
  const int g = lane >> 4;            // lane group 0..3
  const int i = lane & 15;

  const ushort_t* qhb = qh + (size_t)buh * V_DIM * KQ_DIM;
  const ushort_t* qlb = ql + (size_t)buh * V_DIM * KQ_DIM;
  const ushort_t* khb = kh + (size_t)buh * V_DIM * KQ_DIM;
  const ushort_t* klb = kl + (size_t)buh * V_DIM * KQ_DIM;
  const ushort_t* vb  = v  + (size_t)buh * V_DIM * KQ_DIM;
  const float* ab = aff + (size_t)bu * V_DIM;

  __shared__ ushort_t klh[32 * 64];
  __shared__ ushort_t kll[32 * 64];
  __shared__ ushort_t vt[80 * 32];

  const int R = rb * 128 + w * 16 + i;

  union { uint4 u4; short8 s8; } qfh0, qfh1, qfl0, qfl1;
  qfh0.u4 = *(const uint4*)(qhb + (size_t)R * 64 + 0 * 32 + 8 * g);
  qfh1.u4 = *(const uint4*)(qhb + (size_t)R * 64 + 1 * 32 + 8 * g);
  qfl0.u4 = *(const uint4*)(qlb + (size_t)R * 64 + 0 * 32 + 8 * g);
  qfl1.u4 = *(const uint4*)(qlb + (size_t)R * 64 + 1 * 32 + 8 * g);

  f32x4 accO0 = {0.f,0.f,0.f,0.f}, accO1 = {0.f,0.f,0.f,0.f};
  f32x4 accO2 = {0.f,0.f,0.f,0.f}, accO3 = {0.f,0.f,0.f,0.f};
  f32x4 accYZ = {0.f,0.f,0.f,0.f};
  const f32x4 zf = {0.f,0.f,0.f,0.f};

  const int ks_s = t >> 4;
  const int ks_k = (t & 15) * 4;
  const int vs_s = t & 31;
  const int vs_d0 = (t >> 5) * 4;

  for (int tile = 0; tile < V_DIM / 32; ++tile) {
    const int s0 = tile * 32;
    __syncthreads();
    {
      const uint2 kvh = *(const uint2*)(khb + (size_t)(s0 + ks_s) * 64 + ks_k);
      const uint2 kvl = *(const uint2*)(klb + (size_t)(s0 + ks_s) * 64 + ks_k);
      const int dsti = ks_s * 64 + (ks_k ^ ((ks_s & 7) << 3));
      *(uint2*)&klh[dsti] = kvh;
      *(uint2*)&kll[dsti] = kvl;
    }
    {
      const float a_s = ab[s0 + vs_s];
      const uint2 vv = *(const uint2*)(vb + (size_t)(s0 + vs_s) * 64 + vs_d0);
      const ushort_t* ve = (const ushort_t*)&vv;
#pragma unroll
      for (int qq = 0; qq < 4; ++qq) {
        const int d = vs_d0 + qq;
        vt[d * 32 + (vs_s ^ (8 * (d & 3)))] = f2bf(a_s * bf2f(ve[qq]));
      }
      if (t < 32) {
        vt[64 * 32 + (vs_s ^ 0)] = f2bf(a_s);
        vt[65 * 32 + (vs_s ^ 8)] = 0x3F80u;
      }
    }
    __syncthreads();

    f32x4 Dst0 = zf, Dst1 = zf;
#pragma unroll
    for (int st = 0; st < 2; ++st) {
      const int srow = st * 16 + i;
      const int i0 = srow * 64 + ((0 * 32 + 8 * g) ^ ((srow & 7) << 3));
      const int i1 = srow * 64 + ((1 * 32 + 8 * g) ^ ((srow & 7) << 3));
      union { uint4 u4; short8 s8; } ah0, ah1, al0, al1;
      ah0.u4 = *(const uint4*)&klh[i0];
      ah1.u4 = *(const uint4*)&klh[i1];
      al0.u4 = *(const uint4*)&kll[i0];
      al1.u4 = *(const uint4*)&kll[i1];
      f32x4 dcur = (st == 0) ? Dst0 : Dst1;
      dcur = __builtin_amdgcn_mfma_f32_16x16x32_bf16(ah0.s8, qfh0.s8, dcur, 0, 0, 0);
      dcur = __builtin_amdgcn_mfma_f32_16x16x32_bf16(ah1.s8, qfh1.s8, dcur, 0, 0, 0);
      dcur = __builtin_amdgcn_mfma_f32_16x16x32_bf16(ah0.s8, qfl0.s8, dcur, 0, 0, 0);
      dcur = __builtin_amdgcn_mfma_f32_16x16x32_bf16(ah1.s8, qfl1.s8, dcur, 0, 0, 0);
      dcur = __builtin_amdgcn_mfma_f32_16x16x32_bf16(al0.s8, qfh0.s8, dcur, 0, 0, 0);
      dcur = __builtin_amdgcn_mfma_f32_16x16x32_bf16(al1.s8, qfh1.s8, dcur, 0, 0, 0);
      if (st == 0) Dst0 = dcur; else Dst1 = dcur;
    }

    float e0[4], e1[4];
#pragma unroll
    for (int j = 0; j < 4; ++j) { e0[j] = __expf(Dst0[j]); e1[j] = __expf(Dst1[j]); }
    uint_t p00 = pack2bf(e0[0], e0[1]), p01 = pack2bf(e0[2], e0[3]);
    uint_t p10 = pack2bf(e1[0], e1[1]), p11 = pack2bf(e1[2], e1[3]);

    union { uint_t u[4]; short8 s8; } wf;
#pragma unroll
    for (int ii = 0; ii < 4; ++ii) {
      const int srcl = i + 16 * (2 * (g & 1) + (ii >> 1));
      const uint_t pe0 = (ii & 1) ? p01 : p00;
      const uint_t pe1 = (ii & 1) ? p11 : p10;
      const uint_t v0 = __shfl((int)pe0, srcl, 64);
      const uint_t v1 = __shfl((int)pe1, srcl, 64);
      wf.u[ii] = (g >= 2) ? v1 : v0;
    }

#pragma unroll
    for (int dt = 0; dt < 5; ++dt) {
      const int d = 16 * dt + i;
      union { uint4 u4; short8 s8; } av;
      av.u4 = *(const uint4*)&vt[d * 32 + 8 * (g ^ (d & 3))];
      f32x4 c = (dt == 0) ? accO0 : (dt == 1) ? accO1 : (dt == 2) ? accO2
                : (dt == 3) ? accO3 : accYZ;
      c = __builtin_amdgcn_mfma_f32_16x16x32_bf16(av.s8, wf.s8, c, 0, 0, 0);
      if (dt == 0) accO0 = c; else if (dt == 1) accO1 = c; else if (dt == 2) accO2 = c;
      else if (dt == 3) accO3 = c; else accYZ = c;
    }
  }

  const float Y = __shfl(accYZ[0], i, 64);
  const float Z = __shfl(accYZ[1], i, 64);
  const float a_r = ab[R];
  const float tt = a_r / Z;
  const float den = tt * Y + EPS_A;
  const float f = tt / den;
  const float g1 = 1.f - a_r;
  const float g2 = a_r * GAIN_F * f;

  const size_t rowoff = ((size_t)bu * V_DIM + R) * C_DIM + head * KQ_DIM;
#pragma unroll
  for (int dt = 0; dt < 4; ++dt) {
    const int d0 = 16 * dt + 4 * g;
    const float4 x = *(const float4*)(vars + rowoff + d0);
    const f32x4 a = (dt == 0) ? accO0 : (dt == 1) ? accO1 : (dt == 2) ? accO2 : accO3;
    float4 o;
    o.x = g1 * x.x + g2 * a[0];
    o.y = g1 * x.y + g2 * a[1];
    o.z = g1 * x.z + g2 * a[2];
    o.w = g1 * x.w + g2 * a[3];
    *(float4*)(out + rowoff + d0) = o;
  }
}

// ------- kernel C: LN2 + MLP via MFMA (3-term), gated in-place ----------
// block: 32 rows, 512 thr (8 waves = 2 row-tiles x 4 col-groups)
__global__ __launch_bounds__(512) void k_mlp_mfma(
    const float* __restrict__ aff,
    const float* __restrict__ ln2g, const float* __restrict__ ln2b,
    const ushort_t* __restrict__ wts,
    const float* __restrict__ m1bias, const float* __restrict__ m2bias,
    const float* __restrict__ s_all, float* __restrict__ io) {
  const int bid = blockIdx.x;
  const int row0 = bid * GROWS;
  const int bu = row0 / V_DIM;
  const int u = bu % U_DIM;
  const int t = threadIdx.x;
  const int w = t >> 6, lane = t & 63, g = lane >> 4, i = lane & 15;

  __shared__ ushort_t bh[GROWS * C_DIM];   // x-stage, then h1-stage
  __shared__ ushort_t bl[GROWS * C_DIM];
  __shared__ float mean_s[GROWS], rstd_s[GROWS];

  const int tr = t >> 4;
  const int tk0 = (t & 15) * 16;
  float xbuf[16];
  {
    float s1 = 0.f, s2 = 0.f;
    const float* xrow = io + (size_t)(row0 + tr) * C_DIM + tk0;
#pragma unroll
    for (int c = 0; c < 4; ++c) {
      const float4 a = *(const float4*)(xrow + 4 * c);
      xbuf[c*4+0]=a.x; xbuf[c*4+1]=a.y; xbuf[c*4+2]=a.z; xbuf[c*4+3]=a.w;
      s1 += (a.x+a.y)+(a.z+a.w);
      s2 += a.x*a.x+a.y*a.y+a.z*a.z+a.w*a.w;
    }
#pragma unroll
    for (int off = 1; off < 16; off <<= 1) { s1 += __shfl_xor(s1, off); s2 += __shfl_xor(s2, off); }
    if ((t & 15) == 0) {
      const float mm = s1 * (1.f / C_DIM);
      const float var = s2 * (1.f / C_DIM) - mm * mm;
      mean_s[tr] = mm; rstd_s[tr] = rsqrtf(var + 1e-5f);
    }
  }
  __syncthreads();
  {
    const float mm = mean_s[tr], rs = rstd_s[tr];
    const float* sp = s_all + (3 * U_DIM + u) * C_DIM + tk0;
#pragma unroll
    for (int h = 0; h < 2; ++h) {
      const float4 ga = *(const float4*)(ln2g + tk0 + 8 * h);
      const float4 gb = *(const float4*)(ln2g + tk0 + 8 * h + 4);
      const float4 ba = *(const float4*)(ln2b + tk0 + 8 * h);
      const float4 bb = *(const float4*)(ln2b + tk0 + 8 * h + 4);
      const float4 sa = *(const float4*)(sp + 8 * h);
      const float4 sb = *(const float4*)(sp + 8 * h + 4);
      const float v0 = ((xbuf[8*h+0]-mm)*rs*ga.x + ba.x) * sa.x;
      const float v1 = ((xbuf[8*h+1]-mm)*rs*ga.y + ba.y) * sa.y;
      const float v2 = ((xbuf[8*h+2]-mm)*rs*ga.z + ba.z) * sa.z;
      const float v3 = ((xbuf[8*h+3]-mm)*rs*ga.w + ba.w) * sa.w;
      const float v4 = ((xbuf[8*h+4]-mm)*rs*gb.x + bb.x) * sb.x;
      const float v5 = ((xbuf[8*h+5]-mm)*rs*gb.y + bb.y) * sb.y;
      const float v6 = ((xbuf[8*h+6]-mm)*rs*gb.z + bb.z) * sb.z;
      const float v7 = ((xbuf[8*h+7]-mm)*rs*gb.w + bb.w) * sb.w;
      const ushort_t h0=f2bf(v0),h1=f2bf(v1),h2=f2bf(v2),h3=f2bf(v3);
      const ushort_t h4=f2bf(v4),h5=f2bf(v5),h6=f2bf(v6),h7=f2bf(v7);
      uint4 ph, pl;
      ph.x=(uint_t)h0|((uint_t)h1<<16); ph.y=(uint_t)h2|((uint_t)h3<<16);
      ph.z=(uint_t)h4|((uint_t)h5<<16); ph.w=(uint_t)h6|((uint_t)h7<<16);
      pl.x=(uint_t)f2bf(v0-bf2f(h0))|((uint_t)f2bf(v1-bf2f(h1))<<16);
      pl.y=(uint_t)f2bf(v2-bf2f(h2))|((uint_t)f2bf(v3-bf2f(h3))<<16);
      pl.z=(uint_t)f2bf(v4-bf2f(h4))|((uint_t)f2bf(v5-bf2f(h5))<<16);
      pl.w=(uint_t)f2bf(v6-bf2f(h6))|((uint_t)f2bf(v7-bf2f(h7))<<16);
      const int dst = tr * C_DIM + ((tk0 + 8 * h) ^ ((tr & 7) << 3));
      *(uint4*)&bh[dst] = ph;
      *(uint4*)&bl[dst] = pl;
    }
  }
  __syncthreads();

  const int mrow = (w & 1) * 16 + i;
  const int swz = (mrow & 7) << 3;
  const int nbase = (w >> 1) * 64;

  // ---- GEMM1: h1 = x @ m1W (3-term), 4 tiles kept ----
  const ushort_t* W1h = wts + (size_t)6 * 65536;
  const ushort_t* W1l = wts + (size_t)7 * 65536;
  f32x4 acc1[4];
#pragma unroll 2
  for (int nt = 0; nt < 4; ++nt) {
    const int nrow = nbase + nt * 16 + i;
    const ushort_t* wr_h = W1h + (size_t)nrow * C_DIM;
    const ushort_t* wr_l = W1l + (size_t)nrow * C_DIM;
    f32x4 acc = {0.f, 0.f, 0.f, 0.f};
#pragma unroll
    for (int kc = 0; kc < 8; ++kc) {
      const int k0 = kc * 32 + 8 * g;
      union { uint4 u4; short8 s8; } afh, afl, bfh, bfl;
      afh.u4 = *(const uint4*)(wr_h + k0);
      afl.u4 = *(const uint4*)(wr_l + k0);
      bfh.u4 = *(const uint4*)&bh[mrow * C_DIM + (k0 ^ swz)];
      bfl.u4 = *(const uint4*)&bl[mrow * C_DIM + (k0 ^ swz)];
      acc = __builtin_amdgcn_mfma_f32_16x16x32_bf16(afh.s8, bfh.s8, acc, 0, 0, 0);
      acc = __builtin_amdgcn_mfma_f32_16x16x32_bf16(afl.s8, bfh.s8, acc, 0, 0, 0);
      acc = __builtin_amdgcn_mfma_f32_16x16x32_bf16(afh.s8, bfl.s8, acc, 0, 0, 0);
    }
    acc1[nt] = acc;
  }
  __syncthreads();   // all reads of bh/bl done — safe to overwrite with h1

  // ---- stage h1 = gelu(y1 + b1) * sm2, hi/lo ----
  {
    const float* s2p = s_all + (4 * U_DIM + u) * C_DIM;
#pragma unroll
    for (int nt = 0; nt < 4; ++nt) {
      const int n0 = nbase + nt * 16 + 4 * g;
      const float4 b4 = *(const float4*)(m1bias + n0);
      const float4 s4 = *(const float4*)(s2p + n0);
      const float v0 = gelu_ex(acc1[nt][0] + b4.x) * s4.x;
      const float v1 = gelu_ex(acc1[nt][1] + b4.y) * s4.y;
      const float v2 = gelu_ex(acc1[nt][2] + b4.z) * s4.z;
      const float v3 = gelu_ex(acc1[nt][3] + b4.w) * s4.w;
      const ushort_t h0=f2bf(v0),h1=f2bf(v1),h2=f2bf(v2),h3=f2bf(v3);
      uint2 ph, pl;
      ph.x=(uint_t)h0|((uint_t)h1<<16); ph.y=(uint_t)h2|((uint_t)h3<<16);
      pl.x=(uint_t)f2bf(v0-bf2f(h0))|((uint_t)f2bf(v1-bf2f(h1))<<16);
      pl.y=(uint_t)f2bf(v2-bf2f(h2))|((uint_t)f2bf(v3-bf2f(h3))<<16);
      const int dst = mrow * C_DIM + (n0 ^ swz);
      *(uint2*)&bh[dst] = ph;
      *(uint2*)&bl[dst] = pl;
    }
  }
  __syncthreads();

  // ---- GEMM2 + epilogue ----
  const ushort_t* W2h = wts + (size_t)8 * 65536;
  const ushort_t* W2l = wts + (size_t)9 * 65536;
  const int R = row0 + mrow;
  const float a_r = aff[R];
  const float ga = 1.f - a_r;
  const float gg = a_r * a_r * GAIN_F;
#pragma unroll 2
  for (int nt = 0; nt < 4; ++nt) {
    const int nrow = nbase + nt * 16 + i;
    const ushort_t* wr_h = W2h + (size_t)nrow * C_DIM;
    const ushort_t* wr_l = W2l + (size_t)nrow * C_DIM;
    f32x4 acc = {0.f, 0.f, 0.f, 0.f};
#pragma unroll
    for (int kc = 0; kc < 8; ++kc) {
      const int k0 = kc * 32 + 8 * g;
      union { uint4 u4; short8 s8; } afh, afl, bfh, bfl;
      afh.u4 = *(const uint4*)(wr_h + k0);
      afl.u4 = *(const uint4*)(wr_l + k0);
      bfh.u4 = *(const uint4*)&bh[mrow * C_DIM + (k0 ^ swz)];
      bfl.u4 = *(const uint4*)&bl[mrow * C_DIM + (k0 ^ swz)];
      acc = __builtin_amdgcn_mfma_f32_16x16x32_bf16(afh.s8, bfh.s8, acc, 0, 0, 0);
      acc = __builtin_amdgcn_mfma_f32_16x16x32_bf16(afl.s8, bfh.s8, acc, 0, 0, 0);
      acc = __builtin_amdgcn_mfma_f32_16x16x32_bf16(afh.s8, bfl.s8, acc, 0, 0, 0);
    }
    const int n0 = nbase + nt * 16 + 4 * g;
    const float4 b4 = *(const float4*)(m2bias + n0);
    const float e0 = gelu_ex(acc[0] + b4.x);
    const float e1 = gelu_ex(acc[1] + b4.y);
    const float e2 = gelu_ex(acc[2] + b4.z);
    const float e3 = gelu_ex(acc[3] + b4.w);
    float* orow = io + (size_t)R * C_DIM + n0;
    const float4 xr = *(const float4*)orow;
    float4 o;
    o.x = ga * xr.x + gg * e0;
    o.y = ga * xr.y + gg * e1;
    o.z = ga * xr.z + gg * e2;
    o.w = ga * xr.w + gg * e3;
    *(float4*)orow = o;
  }
}

extern "C" void kernel_launch(void* const* d_in, const int* in_sizes, int n_in,
                              void* d_out, int out_size, void* d_ws, size_t ws_size,
                              hipStream_t stream) {
  const float* vars  = (const float*)d_in[0];
  const float* codes = (const float*)d_in[1];
  const float* aff   = (const float*)d_in[2];
  const float* ln1g  = (const float*)d_in[3];
  const float* ln1b  = (const float*)d_in[4];
  const float* ln2g  = (const float*)d_in[5];
  const float* ln2b  = (const float*)d_in[6];
  const float* qWc   = (const float*)d_in[7];
  const float* qW    = (const float*)d_in[8];
  const float* kWc   = (const float*)d_in[9];
  const float* kW    = (const float*)d_in[10];
  const float* vWc   = (const float*)d_in[11];
  const float* vW    = (const float*)d_in[12];
  const float* vb    = (const float*)d_in[13];
  const float* m1Wc  = (const float*)d_in[14];
  const float* m1W   = (const float*)d_in[15];
  const float* m1b   = (const float*)d_in[16];
  const float* m2Wc  = (const float*)d_in[17];
  const float* m2W   = (const float*)d_in[18];
  const float* m2b   = (const float*)d_in[19];
  float* out = (float*)d_out;

  const size_t headsz = (size_t)BUH * V_DIM * KQ_DIM;     // 4.19M elems
  const size_t s_all_sz = 5 * U_DIM * C_DIM;              // 10240 floats

  float* s_all = (float*)d_ws;
  ushort_t* wts = (ushort_t*)(s_all + s_all_sz);          // 10*65536 ushorts
  ushort_t* qh = wts + (size_t)10 * 65536;
  ushort_t* ql = qh + headsz;
  ushort_t* kh = ql + headsz;
  ushort_t* kl = kh + headsz;
  ushort_t* vo = kl + headsz;

  k_wprep<<<80, 256, 0, stream>>>(qW, kW, vW, m1W, m2W, wts);
  k_scales<<<5 * U_DIM, 256, 0, stream>>>(codes, qWc, kWc, vWc, m1Wc, m2Wc, s_all);
  k_qkv_mfma<<<(B_DIM * U_DIM * V_DIM) / GROWS, 512, 0, stream>>>(
      vars, ln1g, ln1b, wts, vb, s_all, qh, ql, kh, kl, vo);
  k_attn_mfma<<<8 * BUH, 512, 0, stream>>>(qh, ql, kh, kl, vo, aff, vars, out);
  k_mlp_mfma<<<(B_DIM * U_DIM * V_DIM) / GROWS, 512, 0, stream>>>(
      aff, ln2g, ln2b, wts, m1b, m2b, s_all, out);
}